// Round 3
// baseline (366.348 us; speedup 1.0000x reference)
//
#include <hip/hip_runtime.h>
#include <math.h>

#define BATCH 2
#define NTOK 4096        // H*W
#define CDIM 256
#define NH 8
#define HD 32
#define MROWS (BATCH * NTOK)   // 8192

typedef __attribute__((ext_vector_type(8))) short bf16x8;
typedef __attribute__((ext_vector_type(4))) float f32x4;
typedef __attribute__((ext_vector_type(4))) unsigned u32x4;

union frag_u { u32x4 u; bf16x8 b; };

__device__ __forceinline__ unsigned short f2bf(float f) {
    union { float f; unsigned u; } x; x.f = f;
    unsigned r = x.u + 0x7FFFu + ((x.u >> 16) & 1u);   // RNE
    return (unsigned short)(r >> 16);
}
__device__ __forceinline__ float bf2f(unsigned short h) {
    union { unsigned u; float f; } x; x.u = ((unsigned)h) << 16; return x.f;
}
__device__ __forceinline__ float exp2_fast(float x) {
    float r;
    asm("v_exp_f32 %0, %1\n\ts_nop 0" : "=v"(r) : "v"(x));   // nop: trans-op hazard
    return r;
}
__device__ __forceinline__ unsigned cvt_pk_bf16(float a, float b) {
    unsigned r;   // r.lo16 = bf16(a), r.hi16 = bf16(b), RNE
    asm("v_cvt_pk_bf16_f32 %0, %1, %2" : "=v"(r) : "v"(a), "v"(b));
    return r;
}
// (a,b) = (tile 2ks dword, tile 2ks+1 dword)  ->  (w0 dword, w1 dword)
__device__ __forceinline__ void permlane_pv(unsigned &a, unsigned &b) {
    asm("s_nop 1\n\t"
        "v_permlane32_swap_b32 %0, %1\n\t"
        "s_nop 1\n\t"
        "v_permlane16_swap_b32 %0, %1" : "+v"(a), "+v"(b));
}

// ---------------- QKV projection GEMM ----------------
// X [8192][256] * Wqkv [256][768] + b ->
//   Q bf16 hi/lo [bh][n][32] (scale*log2e folded), K bf16 hi/lo [bh][n][32],
//   V bf16 hi/lo [bh][32][n] (transposed)
#define BM 64
#define BN 64
#define BK 64

__global__ __launch_bounds__(256) void qkv_gemm(
    const float* __restrict__ X, const float* __restrict__ W,
    const float* __restrict__ bias,
    unsigned short* __restrict__ Qhi, unsigned short* __restrict__ Qlo,
    unsigned short* __restrict__ Khi, unsigned short* __restrict__ Klo,
    unsigned short* __restrict__ Vhi, unsigned short* __restrict__ Vlo)
{
    __shared__ float As[BK][BM + 4];
    __shared__ float Bs[BK][BN + 4];

    const int tid = threadIdx.x;
    const int tx = tid & 15;
    const int ty = tid >> 4;
    const int row0 = blockIdx.x * BM;
    const int col0 = blockIdx.y * BN;

    float c[4][4] = {};

    for (int k0 = 0; k0 < CDIM; k0 += BK) {
        #pragma unroll
        for (int i = 0; i < 4; ++i) {
            int l = tid + i * 256;
            int r = l >> 4;
            int k4 = (l & 15) << 2;
            float4 v = *(const float4*)&X[(size_t)(row0 + r) * CDIM + k0 + k4];
            As[k4 + 0][r] = v.x; As[k4 + 1][r] = v.y;
            As[k4 + 2][r] = v.z; As[k4 + 3][r] = v.w;
        }
        #pragma unroll
        for (int i = 0; i < 4; ++i) {
            int l = tid + i * 256;
            int r = l >> 4;
            int c4 = (l & 15) << 2;
            *(float4*)&Bs[r][c4] = *(const float4*)&W[(size_t)(k0 + r) * 768 + col0 + c4];
        }
        __syncthreads();

        #pragma unroll 16
        for (int kk = 0; kk < BK; ++kk) {
            float4 a = *(const float4*)&As[kk][ty << 2];
            float4 b = *(const float4*)&Bs[kk][tx << 2];
            float av[4] = {a.x, a.y, a.z, a.w};
            float bv[4] = {b.x, b.y, b.z, b.w};
            #pragma unroll
            for (int i = 0; i < 4; ++i)
                #pragma unroll
                for (int j = 0; j < 4; ++j)
                    c[i][j] = fmaf(av[i], bv[j], c[i][j]);
        }
        __syncthreads();
    }

    const int s = col0 >> 8;            // 0=Q 1=K 2=V
    const int b_ = row0 >> 12;
    const int n0 = (row0 & (NTOK - 1)) + (ty << 2);
    const int gc0 = col0 + (tx << 2);
    const int h  = (gc0 >> 5) & 7;
    const int e0 = gc0 & 31;
    const int bh = b_ * NH + h;
    // scale/sqrt(hd) * log2(e): QK^T lands directly in log2 domain
    const float QSC = (float)(1.4426950408889634 / 5.656854249492381);

    if (s == 0) {
        #pragma unroll
        for (int i = 0; i < 4; ++i) {
            unsigned short hh[4], ll[4];
            #pragma unroll
            for (int j = 0; j < 4; ++j) {
                float v = (c[i][j] + bias[gc0 + j]) * QSC;
                hh[j] = f2bf(v);
                ll[j] = f2bf(v - bf2f(hh[j]));
            }
            size_t idx = ((size_t)bh * NTOK + n0 + i) * HD + e0;
            uint2 hw; hw.x = hh[0] | ((unsigned)hh[1] << 16); hw.y = hh[2] | ((unsigned)hh[3] << 16);
            uint2 lw; lw.x = ll[0] | ((unsigned)ll[1] << 16); lw.y = ll[2] | ((unsigned)ll[3] << 16);
            *(uint2*)&Qhi[idx] = hw;
            *(uint2*)&Qlo[idx] = lw;
        }
    } else if (s == 1) {
        #pragma unroll
        for (int i = 0; i < 4; ++i) {
            unsigned short hh[4], ll[4];
            #pragma unroll
            for (int j = 0; j < 4; ++j) {
                float v = c[i][j] + bias[gc0 + j];
                hh[j] = f2bf(v);
                ll[j] = f2bf(v - bf2f(hh[j]));
            }
            size_t idx = ((size_t)bh * NTOK + n0 + i) * HD + e0;
            uint2 hw; hw.x = hh[0] | ((unsigned)hh[1] << 16); hw.y = hh[2] | ((unsigned)hh[3] << 16);
            uint2 lw; lw.x = ll[0] | ((unsigned)ll[1] << 16); lw.y = ll[2] | ((unsigned)ll[3] << 16);
            *(uint2*)&Khi[idx] = hw;
            *(uint2*)&Klo[idx] = lw;
        }
    } else {
        // V transposed: [bh][e][n]
        #pragma unroll
        for (int j = 0; j < 4; ++j) {
            unsigned short hh[4], ll[4];
            #pragma unroll
            for (int i = 0; i < 4; ++i) {
                float v = c[i][j] + bias[gc0 + j];
                hh[i] = f2bf(v);
                ll[i] = f2bf(v - bf2f(hh[i]));
            }
            size_t idx = ((size_t)bh * HD + e0 + j) * NTOK + n0;
            uint2 hw; hw.x = hh[0] | ((unsigned)hh[1] << 16); hw.y = hh[2] | ((unsigned)hh[3] << 16);
            uint2 lw; lw.x = ll[0] | ((unsigned)ll[1] << 16); lw.y = ll[2] | ((unsigned)ll[3] << 16);
            *(uint2*)&Vhi[idx] = hw;
            *(uint2*)&Vlo[idx] = lw;
        }
    }
}

// ---------------- Register-resident MFMA flash attention ----------------
// No LDS. One wave owns 64 q-rows (4 q-tiles of 16). K double-buffered in
// registers, V single-buffered, P redistributed C-frag -> B-frag via
// permlane32_swap + permlane16_swap. All inputs bf16 hi/lo, 3-term split MFMA.
__global__ __launch_bounds__(256) void attn_reg(
    const unsigned short* __restrict__ Qhi, const unsigned short* __restrict__ Qlo,
    const unsigned short* __restrict__ Khi, const unsigned short* __restrict__ Klo,
    const unsigned short* __restrict__ Vhi, const unsigned short* __restrict__ Vlo,
    float* __restrict__ AO)
{
    const int tid = threadIdx.x;
    const int w  = tid >> 6;
    const int lq = tid & 15;
    const int g  = (tid & 63) >> 4;
    const int bx = blockIdx.x;
    const int bh = bx & 15;          // bh fastest -> same-head blocks share XCD
    const int qc = bx >> 4;
    const int q0 = (qc * 4 + w) * 64;
    const size_t kb = (size_t)bh * (NTOK * HD);
    const size_t vb = (size_t)bh * (HD * NTOK);

    // ---- Q fragments (pre-scaled by scale*log2e in qkv epilogue) ----
    bf16x8 qh[4], qlo[4];
    #pragma unroll
    for (int qt = 0; qt < 4; ++qt) {
        size_t qi = kb + (size_t)(q0 + qt * 16 + lq) * HD + g * 8;
        qh[qt]  = *(const bf16x8*)(Qhi + qi);
        qlo[qt] = *(const bf16x8*)(Qlo + qi);
    }

    f32x4 o[4][2] = {};
    float m_[4]   = {-1e30f, -1e30f, -1e30f, -1e30f};
    float lsum[4] = {0.f, 0.f, 0.f, 0.f};

    // ---- K register double buffer: prologue load of step 0 ----
    bf16x8 kAh[4], kAl[4], kBh[4], kBl[4];
    #pragma unroll
    for (int t = 0; t < 4; ++t) {
        size_t ki = kb + (size_t)(16 * t + lq) * HD + g * 8;
        kAh[t] = *(const bf16x8*)(Khi + ki);
        kAl[t] = *(const bf16x8*)(Klo + ki);
    }

#define ATTN_STEP(CURH, CURL, NXTH, NXTL, SS)                                         \
    {                                                                                 \
        const int kv0 = (SS) * 64;                                                    \
        /* V tile for this step */                                                    \
        frag_u vhf[2][2], vlf[2][2];                                                  \
        _Pragma("unroll")                                                             \
        for (int mt = 0; mt < 2; ++mt) {                                              \
            _Pragma("unroll")                                                         \
            for (int ks = 0; ks < 2; ++ks) {                                          \
                size_t vi = vb + (size_t)(16 * mt + lq) * NTOK + kv0 + ks * 32 + g * 8; \
                vhf[mt][ks].b = *(const bf16x8*)(Vhi + vi);                           \
                vlf[mt][ks].b = *(const bf16x8*)(Vlo + vi);                           \
            }                                                                         \
        }                                                                             \
        /* prefetch next K tile (tail read stays inside workspace) */                 \
        _Pragma("unroll")                                                             \
        for (int t = 0; t < 4; ++t) {                                                 \
            size_t ki = kb + (size_t)(kv0 + 64 + 16 * t + lq) * HD + g * 8;           \
            NXTH[t] = *(const bf16x8*)(Khi + ki);                                     \
            NXTL[t] = *(const bf16x8*)(Klo + ki);                                     \
        }                                                                             \
        _Pragma("unroll")                                                             \
        for (int qt = 0; qt < 4; ++qt) {                                              \
            f32x4 sc[4];                                                              \
            _Pragma("unroll")                                                         \
            for (int t = 0; t < 4; ++t) {                                             \
                f32x4 cc = {0.f, 0.f, 0.f, 0.f};                                      \
                cc = __builtin_amdgcn_mfma_f32_16x16x32_bf16(CURH[t], qh[qt], cc, 0, 0, 0);  \
                cc = __builtin_amdgcn_mfma_f32_16x16x32_bf16(CURH[t], qlo[qt], cc, 0, 0, 0); \
                cc = __builtin_amdgcn_mfma_f32_16x16x32_bf16(CURL[t], qh[qt], cc, 0, 0, 0);  \
                sc[t] = cc;                                                           \
            }                                                                         \
            float mx = fmaxf(                                                         \
                fmaxf(fmaxf(fmaxf(sc[0][0], sc[0][1]), fmaxf(sc[0][2], sc[0][3])),    \
                      fmaxf(fmaxf(sc[1][0], sc[1][1]), fmaxf(sc[1][2], sc[1][3]))),   \
                fmaxf(fmaxf(fmaxf(sc[2][0], sc[2][1]), fmaxf(sc[2][2], sc[2][3])),    \
                      fmaxf(fmaxf(sc[3][0], sc[3][1]), fmaxf(sc[3][2], sc[3][3]))));  \
            mx = fmaxf(mx, __shfl_xor(mx, 16));                                       \
            mx = fmaxf(mx, __shfl_xor(mx, 32));                                       \
            mx = fmaxf(mx, m_[qt]);                                                   \
            float rs = exp2_fast(m_[qt] - mx);                                        \
            m_[qt] = mx;                                                              \
            lsum[qt] *= rs;                                                           \
            o[qt][0] *= rs;                                                           \
            o[qt][1] *= rs;                                                           \
            unsigned ph[4][2], pl[4][2];                                              \
            _Pragma("unroll")                                                         \
            for (int t = 0; t < 4; ++t) {                                             \
                float p0 = exp2_fast(sc[t][0] - mx);                                  \
                float p1 = exp2_fast(sc[t][1] - mx);                                  \
                float p2 = exp2_fast(sc[t][2] - mx);                                  \
                float p3 = exp2_fast(sc[t][3] - mx);                                  \
                lsum[qt] += (p0 + p1) + (p2 + p3);                                    \
                unsigned d0 = cvt_pk_bf16(p0, p1);                                    \
                unsigned d1 = cvt_pk_bf16(p2, p3);                                    \
                union { unsigned u; float f; } t0, t1;                                \
                t0.u = d0 << 16;          float e0 = p0 - t0.f;                       \
                t1.u = d0 & 0xFFFF0000u;  float e1 = p1 - t1.f;                       \
                unsigned l0 = cvt_pk_bf16(e0, e1);                                    \
                t0.u = d1 << 16;          e0 = p2 - t0.f;                             \
                t1.u = d1 & 0xFFFF0000u;  e1 = p3 - t1.f;                             \
                unsigned l1 = cvt_pk_bf16(e0, e1);                                    \
                ph[t][0] = d0; ph[t][1] = d1;                                         \
                pl[t][0] = l0; pl[t][1] = l1;                                         \
            }                                                                         \
            _Pragma("unroll")                                                         \
            for (int ks = 0; ks < 2; ++ks) {                                          \
                unsigned h00 = ph[2 * ks][0], h10 = ph[2 * ks + 1][0];                \
                unsigned h01 = ph[2 * ks][1], h11 = ph[2 * ks + 1][1];                \
                permlane_pv(h00, h10);                                                \
                permlane_pv(h01, h11);                                                \
                frag_u PH; PH.u = (u32x4){h00, h01, h10, h11};                        \
                unsigned q00 = pl[2 * ks][0], q10 = pl[2 * ks + 1][0];                \
                unsigned q01 = pl[2 * ks][1], q11 = pl[2 * ks + 1][1];                \
                permlane_pv(q00, q10);                                                \
                permlane_pv(q01, q11);                                                \
                frag_u PL; PL.u = (u32x4){q00, q01, q10, q11};                        \
                _Pragma("unroll")                                                     \
                for (int mt = 0; mt < 2; ++mt) {                                      \
                    o[qt][mt] = __builtin_amdgcn_mfma_f32_16x16x32_bf16(vhf[mt][ks].b, PH.b, o[qt][mt], 0, 0, 0); \
                    o[qt][mt] = __builtin_amdgcn_mfma_f32_16x16x32_bf16(vhf[mt][ks].b, PL.b, o[qt][mt], 0, 0, 0); \
                    o[qt][mt] = __builtin_amdgcn_mfma_f32_16x16x32_bf16(vlf[mt][ks].b, PH.b, o[qt][mt], 0, 0, 0); \
                }                                                                     \
            }                                                                         \
        }                                                                             \
    }

    for (int s = 0; s < 64; s += 2) {
        ATTN_STEP(kAh, kAl, kBh, kBl, s);
        ATTN_STEP(kBh, kBl, kAh, kAl, s + 1);
    }
#undef ATTN_STEP

    // ---- finalize ----
    const int b_ = bh >> 3, h_ = bh & 7;
    #pragma unroll
    for (int qt = 0; qt < 4; ++qt) {
        float ls = lsum[qt];
        ls += __shfl_xor(ls, 16);
        ls += __shfl_xor(ls, 32);
        float inv = 1.0f / ls;
        int qg = q0 + qt * 16 + lq;
        #pragma unroll
        for (int mt = 0; mt < 2; ++mt) {
            float4 st;
            st.x = o[qt][mt][0] * inv;
            st.y = o[qt][mt][1] * inv;
            st.z = o[qt][mt][2] * inv;
            st.w = o[qt][mt][3] * inv;
            *(float4*)&AO[((size_t)b_ * NTOK + qg) * CDIM + h_ * 32 + mt * 16 + g * 4] = st;
        }
    }
}

// ---------------- Output projection GEMM ----------------
__global__ __launch_bounds__(256) void proj_gemm(
    const float* __restrict__ A, const float* __restrict__ W,
    const float* __restrict__ bias, float* __restrict__ out)
{
    __shared__ float As[BK][BM + 4];
    __shared__ float Bs[BK][BN + 4];

    const int tid = threadIdx.x;
    const int tx = tid & 15;
    const int ty = tid >> 4;
    const int row0 = blockIdx.x * BM;
    const int col0 = blockIdx.y * BN;

    float c[4][4] = {};

    for (int k0 = 0; k0 < CDIM; k0 += BK) {
        #pragma unroll
        for (int i = 0; i < 4; ++i) {
            int l = tid + i * 256;
            int r = l >> 4;
            int k4 = (l & 15) << 2;
            float4 v = *(const float4*)&A[(size_t)(row0 + r) * CDIM + k0 + k4];
            As[k4 + 0][r] = v.x; As[k4 + 1][r] = v.y;
            As[k4 + 2][r] = v.z; As[k4 + 3][r] = v.w;
        }
        #pragma unroll
        for (int i = 0; i < 4; ++i) {
            int l = tid + i * 256;
            int r = l >> 4;
            int c4 = (l & 15) << 2;
            *(float4*)&Bs[r][c4] = *(const float4*)&W[(size_t)(k0 + r) * CDIM + col0 + c4];
        }
        __syncthreads();

        #pragma unroll 16
        for (int kk = 0; kk < BK; ++kk) {
            float4 a = *(const float4*)&As[kk][ty << 2];
            float4 b = *(const float4*)&Bs[kk][tx << 2];
            float av[4] = {a.x, a.y, a.z, a.w};
            float bv[4] = {b.x, b.y, b.z, b.w};
            #pragma unroll
            for (int i = 0; i < 4; ++i)
                #pragma unroll
                for (int j = 0; j < 4; ++j)
                    c[i][j] = fmaf(av[i], bv[j], c[i][j]);
        }
        __syncthreads();
    }

    #pragma unroll
    for (int i = 0; i < 4; ++i) {
        int gr = row0 + (ty << 2) + i;
        #pragma unroll
        for (int j = 0; j < 4; ++j) {
            int gc = col0 + (tx << 2) + j;
            out[(size_t)gr * CDIM + gc] = c[i][j] + bias[gc];
        }
    }
}

extern "C" void kernel_launch(void* const* d_in, const int* in_sizes, int n_in,
                              void* d_out, int out_size, void* d_ws, size_t ws_size,
                              hipStream_t stream)
{
    const float* x      = (const float*)d_in[0];
    const float* w_qkv  = (const float*)d_in[1];
    const float* b_qkv  = (const float*)d_in[2];
    const float* w_proj = (const float*)d_in[3];
    const float* b_proj = (const float*)d_in[4];
    // d_in[5] rel_bias: per-head scalar over the full score matrix -> softmax no-op.

    float* out = (float*)d_out;

    // ws: Qhi|Qlo|Khi|Klo|Vhi|Vlo (4MB each, bf16) + AO (8MB f32) = 32MB
    const size_t NE = (size_t)BATCH * NH * NTOK * HD;   // 2,097,152
    char* p = (char*)d_ws;
    unsigned short* Qhi = (unsigned short*)p;  p += NE * 2;
    unsigned short* Qlo = (unsigned short*)p;  p += NE * 2;
    unsigned short* Khi = (unsigned short*)p;  p += NE * 2;
    unsigned short* Klo = (unsigned short*)p;  p += NE * 2;
    unsigned short* Vhi = (unsigned short*)p;  p += NE * 2;
    unsigned short* Vlo = (unsigned short*)p;  p += NE * 2;
    float* AO           = (float*)p;

    {
        dim3 grid(MROWS / BM, 768 / BN);   // 128 x 12
        qkv_gemm<<<grid, 256, 0, stream>>>(x, w_qkv, b_qkv, Qhi, Qlo, Khi, Klo, Vhi, Vlo);
    }
    {
        dim3 grid(256);                    // bh = bx & 15 (XCD locality), qc = bx >> 4
        attn_reg<<<grid, 256, 0, stream>>>(Qhi, Qlo, Khi, Klo, Vhi, Vlo, AO);
    }
    {
        dim3 grid(MROWS / BM, CDIM / BN);  // 128 x 4
        proj_gemm<<<grid, 256, 0, stream>>>(AO, w_proj, b_proj, out);
    }
}

// Round 4
// 316.620 us; speedup vs baseline: 1.1571x; 1.1571x over previous
//
#include <hip/hip_runtime.h>
#include <math.h>

#define BATCH 2
#define NTOK 4096        // H*W
#define CDIM 256
#define NH 8
#define HD 32
#define MROWS (BATCH * NTOK)   // 8192

typedef __attribute__((ext_vector_type(8))) short bf16x8;
typedef __attribute__((ext_vector_type(4))) float f32x4;
typedef __attribute__((ext_vector_type(4))) unsigned u32x4;

union frag_u { uint4 q; u32x4 u; bf16x8 b; };

__device__ __forceinline__ unsigned short f2bf(float f) {
    union { float f; unsigned u; } x; x.f = f;
    unsigned r = x.u + 0x7FFFu + ((x.u >> 16) & 1u);   // RNE
    return (unsigned short)(r >> 16);
}
__device__ __forceinline__ float bf2f(unsigned short h) {
    union { unsigned u; float f; } x; x.u = ((unsigned)h) << 16; return x.f;
}
__device__ __forceinline__ float exp2_fast(float x) {
    float r;
    asm("v_exp_f32 %0, %1\n\ts_nop 0" : "=v"(r) : "v"(x));   // proven in r2/r3
    return r;
}
__device__ __forceinline__ unsigned cvt_pk_bf16(float a, float b) {
    unsigned r;   // lo16 = bf16(a), hi16 = bf16(b), RNE
    asm("v_cvt_pk_bf16_f32 %0, %1, %2" : "=v"(r) : "v"(a), "v"(b));
    return r;
}
// C-frag dword pair (tile 2ks, tile 2ks+1) -> B-frag dword pair (w0, w1); proven r3
__device__ __forceinline__ void permlane_pv(unsigned &a, unsigned &b) {
    asm("s_nop 1\n\t"
        "v_permlane32_swap_b32 %0, %1\n\t"
        "s_nop 1\n\t"
        "v_permlane16_swap_b32 %0, %1" : "+v"(a), "+v"(b));
}

// ---------------- QKV projection GEMM ----------------
// X [8192][256] * Wqkv [256][768] + b ->
//   Q bf16 hi/lo [bh][n][32] (scale*log2e folded), K bf16 hi/lo [bh][n][32],
//   V bf16 hi/lo [bh][32][n] (transposed)
#define BM 64
#define BN 64
#define BK 64

__global__ __launch_bounds__(256) void qkv_gemm(
    const float* __restrict__ X, const float* __restrict__ W,
    const float* __restrict__ bias,
    unsigned short* __restrict__ Qhi, unsigned short* __restrict__ Qlo,
    unsigned short* __restrict__ Khi, unsigned short* __restrict__ Klo,
    unsigned short* __restrict__ Vhi, unsigned short* __restrict__ Vlo)
{
    __shared__ float As[BK][BM + 4];
    __shared__ float Bs[BK][BN + 4];

    const int tid = threadIdx.x;
    const int tx = tid & 15;
    const int ty = tid >> 4;
    const int row0 = blockIdx.x * BM;
    const int col0 = blockIdx.y * BN;

    float c[4][4] = {};

    for (int k0 = 0; k0 < CDIM; k0 += BK) {
        #pragma unroll
        for (int i = 0; i < 4; ++i) {
            int l = tid + i * 256;
            int r = l >> 4;
            int k4 = (l & 15) << 2;
            float4 v = *(const float4*)&X[(size_t)(row0 + r) * CDIM + k0 + k4];
            As[k4 + 0][r] = v.x; As[k4 + 1][r] = v.y;
            As[k4 + 2][r] = v.z; As[k4 + 3][r] = v.w;
        }
        #pragma unroll
        for (int i = 0; i < 4; ++i) {
            int l = tid + i * 256;
            int r = l >> 4;
            int c4 = (l & 15) << 2;
            *(float4*)&Bs[r][c4] = *(const float4*)&W[(size_t)(k0 + r) * 768 + col0 + c4];
        }
        __syncthreads();

        #pragma unroll 16
        for (int kk = 0; kk < BK; ++kk) {
            float4 a = *(const float4*)&As[kk][ty << 2];
            float4 b = *(const float4*)&Bs[kk][tx << 2];
            float av[4] = {a.x, a.y, a.z, a.w};
            float bv[4] = {b.x, b.y, b.z, b.w};
            #pragma unroll
            for (int i = 0; i < 4; ++i)
                #pragma unroll
                for (int j = 0; j < 4; ++j)
                    c[i][j] = fmaf(av[i], bv[j], c[i][j]);
        }
        __syncthreads();
    }

    const int s = col0 >> 8;            // 0=Q 1=K 2=V
    const int b_ = row0 >> 12;
    const int n0 = (row0 & (NTOK - 1)) + (ty << 2);
    const int gc0 = col0 + (tx << 2);
    const int h  = (gc0 >> 5) & 7;
    const int e0 = gc0 & 31;
    const int bh = b_ * NH + h;
    // scale/sqrt(hd) * log2(e): QK^T lands directly in log2 domain
    const float QSC = (float)(1.4426950408889634 / 5.656854249492381);

    if (s == 0) {
        #pragma unroll
        for (int i = 0; i < 4; ++i) {
            unsigned short hh[4], ll[4];
            #pragma unroll
            for (int j = 0; j < 4; ++j) {
                float v = (c[i][j] + bias[gc0 + j]) * QSC;
                hh[j] = f2bf(v);
                ll[j] = f2bf(v - bf2f(hh[j]));
            }
            size_t idx = ((size_t)bh * NTOK + n0 + i) * HD + e0;
            uint2 hw; hw.x = hh[0] | ((unsigned)hh[1] << 16); hw.y = hh[2] | ((unsigned)hh[3] << 16);
            uint2 lw; lw.x = ll[0] | ((unsigned)ll[1] << 16); lw.y = ll[2] | ((unsigned)ll[3] << 16);
            *(uint2*)&Qhi[idx] = hw;
            *(uint2*)&Qlo[idx] = lw;
        }
    } else if (s == 1) {
        #pragma unroll
        for (int i = 0; i < 4; ++i) {
            unsigned short hh[4], ll[4];
            #pragma unroll
            for (int j = 0; j < 4; ++j) {
                float v = c[i][j] + bias[gc0 + j];
                hh[j] = f2bf(v);
                ll[j] = f2bf(v - bf2f(hh[j]));
            }
            size_t idx = ((size_t)bh * NTOK + n0 + i) * HD + e0;
            uint2 hw; hw.x = hh[0] | ((unsigned)hh[1] << 16); hw.y = hh[2] | ((unsigned)hh[3] << 16);
            uint2 lw; lw.x = ll[0] | ((unsigned)ll[1] << 16); lw.y = ll[2] | ((unsigned)ll[3] << 16);
            *(uint2*)&Khi[idx] = hw;
            *(uint2*)&Klo[idx] = lw;
        }
    } else {
        // V transposed: [bh][e][n]
        #pragma unroll
        for (int j = 0; j < 4; ++j) {
            unsigned short hh[4], ll[4];
            #pragma unroll
            for (int i = 0; i < 4; ++i) {
                float v = c[i][j] + bias[gc0 + j];
                hh[i] = f2bf(v);
                ll[i] = f2bf(v - bf2f(hh[i]));
            }
            size_t idx = ((size_t)bh * HD + e0 + j) * NTOK + n0;
            uint2 hw; hw.x = hh[0] | ((unsigned)hh[1] << 16); hw.y = hh[2] | ((unsigned)hh[3] << 16);
            uint2 lw; lw.x = ll[0] | ((unsigned)ll[1] << 16); lw.y = ll[2] | ((unsigned)ll[3] << 16);
            *(uint2*)&Vhi[idx] = hw;
            *(uint2*)&Vlo[idx] = lw;
        }
    }
}

// ---------------- MFMA flash attention, in-block KV-split ----------------
// Block = 4 waves over 64 q-rows. Wave w: q-pair (w&1), kv-half (w>>1), 32
// steps of 64 kv. K staged in LDS (reg-double-buffered); V fragments read
// straight from L2 (issued early, consumed after QK^T+softmax). P is single
// bf16 redistributed C-frag->B-frag via permlane (proven r3). End: partial
// (m, l, O) merge between wave pairs (0,2) and (1,3) through LDS.
__global__ __launch_bounds__(256, 3) void attn_split(
    const unsigned short* __restrict__ Qhi, const unsigned short* __restrict__ Qlo,
    const unsigned short* __restrict__ Khi, const unsigned short* __restrict__ Klo,
    const unsigned short* __restrict__ Vhi, const unsigned short* __restrict__ Vlo,
    float* __restrict__ AO)
{
    __shared__ __align__(16) char SM[20480];   // K stage [2 str][hi/lo]; merge alias
    unsigned short (*KsH)[64][40] = (unsigned short (*)[64][40])(SM);
    unsigned short (*KsL)[64][40] = (unsigned short (*)[64][40])(SM + 10240);

    const int tid = threadIdx.x;
    const int w = tid >> 6, lane = tid & 63, lq = lane & 15, g = lane >> 4;
    const int qpair = w & 1, str = w >> 1;
    const int bx = blockIdx.x;
    const int bh = bx & 15, qc = bx >> 4;     // same-head blocks share XCD L2
    const int q0 = qc * 64 + qpair * 32;
    const size_t kb = (size_t)bh * (NTOK * HD);
    const size_t vb = (size_t)bh * (HD * NTOK);
    const int kvbase = str * 2048;

    // ---- Q fragments (pre-scaled by scale*log2e) ----
    bf16x8 qh[2], qlo[2];
    #pragma unroll
    for (int qt = 0; qt < 2; ++qt) {
        size_t qi = kb + (size_t)(q0 + qt * 16 + lq) * HD + g * 8;
        qh[qt]  = *(const bf16x8*)(Qhi + qi);
        qlo[qt] = *(const bf16x8*)(Qlo + qi);
    }

    // ---- K staging addresses (fixed LDS ptrs; global walks by step) ----
    size_t gK[2];
    unsigned short *lKH[2], *lKL[2];
    #pragma unroll
    for (int i = 0; i < 2; ++i) {
        int f = tid + i * 256;
        int s = f >> 8, r = (f >> 2) & 63, c = f & 3;
        gK[i]  = kb + (size_t)(s * 2048 + r) * HD + c * 8;
        lKH[i] = &KsH[s][r][c * 8];
        lKL[i] = &KsL[s][r][c * 8];
    }
    uint4 kstH[2], kstL[2];
    #pragma unroll
    for (int i = 0; i < 2; ++i) {
        kstH[i] = *(const uint4*)(Khi + gK[i]);
        kstL[i] = *(const uint4*)(Klo + gK[i]);
    }

    // ---- V fragment base addresses ----
    size_t vbase[2][2];
    #pragma unroll
    for (int mt = 0; mt < 2; ++mt)
        #pragma unroll
        for (int ks = 0; ks < 2; ++ks)
            vbase[mt][ks] = vb + (size_t)(16 * mt + lq) * NTOK + kvbase + ks * 32 + g * 8;

    f32x4 o[2][2] = {};
    f32x4 lacc[2] = {};
    float m_[2] = {-1e30f, -1e30f};

    for (int step = 0; step < 32; ++step) {
        __syncthreads();                       // previous compute done with K LDS
        #pragma unroll
        for (int i = 0; i < 2; ++i) {
            *(uint4*)lKH[i] = kstH[i];
            *(uint4*)lKL[i] = kstL[i];
        }
        __syncthreads();                       // K tile visible

        // prefetch next K tile into regs (last-step overrun stays inside ws)
        {
            size_t po = (size_t)(step + 1) * 2048;
            #pragma unroll
            for (int i = 0; i < 2; ++i) {
                kstH[i] = *(const uint4*)(Khi + gK[i] + po);
                kstL[i] = *(const uint4*)(Klo + gK[i] + po);
            }
        }

        // issue V loads for this step early (consumed after QK^T + softmax)
        frag_u vh[2][2], vl[2][2];
        {
            int vo = step * 64;
            #pragma unroll
            for (int mt = 0; mt < 2; ++mt)
                #pragma unroll
                for (int ks = 0; ks < 2; ++ks) {
                    vh[mt][ks].q = *(const uint4*)(Vhi + vbase[mt][ks] + vo);
                    vl[mt][ks].q = *(const uint4*)(Vlo + vbase[mt][ks] + vo);
                }
        }

        // K fragments from LDS
        bf16x8 kh[4], kl[4];
        #pragma unroll
        for (int t = 0; t < 4; ++t) {
            kh[t] = *(const bf16x8*)&KsH[str][16 * t + lq][g * 8];
            kl[t] = *(const bf16x8*)&KsL[str][16 * t + lq][g * 8];
        }

        #pragma unroll
        for (int qt = 0; qt < 2; ++qt) {
            // QK^T (3-term split)
            f32x4 sc[4];
            #pragma unroll
            for (int t = 0; t < 4; ++t) {
                f32x4 cc = {0.f, 0.f, 0.f, 0.f};
                cc = __builtin_amdgcn_mfma_f32_16x16x32_bf16(kh[t], qh[qt],  cc, 0, 0, 0);
                cc = __builtin_amdgcn_mfma_f32_16x16x32_bf16(kh[t], qlo[qt], cc, 0, 0, 0);
                cc = __builtin_amdgcn_mfma_f32_16x16x32_bf16(kl[t], qh[qt],  cc, 0, 0, 0);
                sc[t] = cc;
            }
            // row max (per q-column lq)
            float mx = fmaxf(
                fmaxf(fmaxf(fmaxf(sc[0][0], sc[0][1]), fmaxf(sc[0][2], sc[0][3])),
                      fmaxf(fmaxf(sc[1][0], sc[1][1]), fmaxf(sc[1][2], sc[1][3]))),
                fmaxf(fmaxf(fmaxf(sc[2][0], sc[2][1]), fmaxf(sc[2][2], sc[2][3])),
                      fmaxf(fmaxf(sc[3][0], sc[3][1]), fmaxf(sc[3][2], sc[3][3]))));
            mx = fmaxf(mx, __shfl_xor(mx, 16));
            mx = fmaxf(mx, __shfl_xor(mx, 32));
            mx = fmaxf(mx, m_[qt]);
            float rs = exp2_fast(m_[qt] - mx);
            m_[qt] = mx;
            lacc[qt] *= rs;
            o[qt][0] *= rs;
            o[qt][1] *= rs;
            // P = exp2(s - m), single bf16
            unsigned ph[4][2];
            #pragma unroll
            for (int t = 0; t < 4; ++t) {
                float p0 = exp2_fast(sc[t][0] - mx);
                float p1 = exp2_fast(sc[t][1] - mx);
                float p2 = exp2_fast(sc[t][2] - mx);
                float p3 = exp2_fast(sc[t][3] - mx);
                lacc[qt] += (f32x4){p0, p1, p2, p3};
                ph[t][0] = cvt_pk_bf16(p0, p1);
                ph[t][1] = cvt_pk_bf16(p2, p3);
            }
            // PV: redistribute P, accumulate O^T
            #pragma unroll
            for (int ks = 0; ks < 2; ++ks) {
                unsigned h00 = ph[2 * ks][0], h10 = ph[2 * ks + 1][0];
                unsigned h01 = ph[2 * ks][1], h11 = ph[2 * ks + 1][1];
                permlane_pv(h00, h10);
                permlane_pv(h01, h11);
                frag_u PH; PH.u = (u32x4){h00, h01, h10, h11};
                #pragma unroll
                for (int mt = 0; mt < 2; ++mt) {
                    o[qt][mt] = __builtin_amdgcn_mfma_f32_16x16x32_bf16(vh[mt][ks].b, PH.b, o[qt][mt], 0, 0, 0);
                    o[qt][mt] = __builtin_amdgcn_mfma_f32_16x16x32_bf16(vl[mt][ks].b, PH.b, o[qt][mt], 0, 0, 0);
                }
            }
        }
    }

    // ---- reduce l across the 4 g-groups ----
    float ls[2];
    #pragma unroll
    for (int qt = 0; qt < 2; ++qt) {
        float s4 = (lacc[qt][0] + lacc[qt][1]) + (lacc[qt][2] + lacc[qt][3]);
        s4 += __shfl_xor(s4, 16);
        s4 += __shfl_xor(s4, 32);
        ls[qt] = s4;
    }

    // ---- intra-block merge of kv-half partials (alias over K stage LDS) ----
    __syncthreads();
    float* mb = (float*)SM + w * 1280 + lane * 20;
    #pragma unroll
    for (int qt = 0; qt < 2; ++qt)
        #pragma unroll
        for (int mt = 0; mt < 2; ++mt)
            *(f32x4*)(mb + qt * 8 + mt * 4) = o[qt][mt];
    *(f32x4*)(mb + 16) = (f32x4){m_[0], m_[1], ls[0], ls[1]};
    __syncthreads();

    if (w < 2) {
        const float* pb = (float*)SM + (w + 2) * 1280 + lane * 20;
        f32x4 pml = *(const f32x4*)(pb + 16);
        const int b_ = bh >> 3, h_ = bh & 7;
        #pragma unroll
        for (int qt = 0; qt < 2; ++qt) {
            float mstar = fmaxf(m_[qt], pml[qt]);
            float wa = exp2_fast(m_[qt] - mstar);
            float wb = exp2_fast(pml[qt] - mstar);
            float lstar = ls[qt] * wa + pml[2 + qt] * wb;
            float inv = 1.0f / lstar;
            int qg = q0 + qt * 16 + lq;
            #pragma unroll
            for (int mt = 0; mt < 2; ++mt) {
                f32x4 po2 = *(const f32x4*)(pb + qt * 8 + mt * 4);
                f32x4 st = (o[qt][mt] * wa + po2 * wb) * inv;
                *(f32x4*)&AO[((size_t)b_ * NTOK + qg) * CDIM + h_ * 32 + mt * 16 + g * 4] = st;
            }
        }
    }
}

// ---------------- Output projection GEMM ----------------
__global__ __launch_bounds__(256) void proj_gemm(
    const float* __restrict__ A, const float* __restrict__ W,
    const float* __restrict__ bias, float* __restrict__ out)
{
    __shared__ float As[BK][BM + 4];
    __shared__ float Bs[BK][BN + 4];

    const int tid = threadIdx.x;
    const int tx = tid & 15;
    const int ty = tid >> 4;
    const int row0 = blockIdx.x * BM;
    const int col0 = blockIdx.y * BN;

    float c[4][4] = {};

    for (int k0 = 0; k0 < CDIM; k0 += BK) {
        #pragma unroll
        for (int i = 0; i < 4; ++i) {
            int l = tid + i * 256;
            int r = l >> 4;
            int k4 = (l & 15) << 2;
            float4 v = *(const float4*)&A[(size_t)(row0 + r) * CDIM + k0 + k4];
            As[k4 + 0][r] = v.x; As[k4 + 1][r] = v.y;
            As[k4 + 2][r] = v.z; As[k4 + 3][r] = v.w;
        }
        #pragma unroll
        for (int i = 0; i < 4; ++i) {
            int l = tid + i * 256;
            int r = l >> 4;
            int c4 = (l & 15) << 2;
            *(float4*)&Bs[r][c4] = *(const float4*)&W[(size_t)(k0 + r) * CDIM + col0 + c4];
        }
        __syncthreads();

        #pragma unroll 16
        for (int kk = 0; kk < BK; ++kk) {
            float4 a = *(const float4*)&As[kk][ty << 2];
            float4 b = *(const float4*)&Bs[kk][tx << 2];
            float av[4] = {a.x, a.y, a.z, a.w};
            float bv[4] = {b.x, b.y, b.z, b.w};
            #pragma unroll
            for (int i = 0; i < 4; ++i)
                #pragma unroll
                for (int j = 0; j < 4; ++j)
                    c[i][j] = fmaf(av[i], bv[j], c[i][j]);
        }
        __syncthreads();
    }

    #pragma unroll
    for (int i = 0; i < 4; ++i) {
        int gr = row0 + (ty << 2) + i;
        #pragma unroll
        for (int j = 0; j < 4; ++j) {
            int gc = col0 + (tx << 2) + j;
            out[(size_t)gr * CDIM + gc] = c[i][j] + bias[gc];
        }
    }
}

extern "C" void kernel_launch(void* const* d_in, const int* in_sizes, int n_in,
                              void* d_out, int out_size, void* d_ws, size_t ws_size,
                              hipStream_t stream)
{
    const float* x      = (const float*)d_in[0];
    const float* w_qkv  = (const float*)d_in[1];
    const float* b_qkv  = (const float*)d_in[2];
    const float* w_proj = (const float*)d_in[3];
    const float* b_proj = (const float*)d_in[4];
    // d_in[5] rel_bias: per-head scalar over the full score matrix -> softmax no-op.

    float* out = (float*)d_out;

    // ws: Qhi|Qlo|Khi|Klo|Vhi|Vlo (4MB each, bf16) + AO (8MB f32) = 32MB
    const size_t NE = (size_t)BATCH * NH * NTOK * HD;   // 2,097,152
    char* p = (char*)d_ws;
    unsigned short* Qhi = (unsigned short*)p;  p += NE * 2;
    unsigned short* Qlo = (unsigned short*)p;  p += NE * 2;
    unsigned short* Khi = (unsigned short*)p;  p += NE * 2;
    unsigned short* Klo = (unsigned short*)p;  p += NE * 2;
    unsigned short* Vhi = (unsigned short*)p;  p += NE * 2;
    unsigned short* Vlo = (unsigned short*)p;  p += NE * 2;
    float* AO           = (float*)p;

    {
        dim3 grid(MROWS / BM, 768 / BN);   // 128 x 12
        qkv_gemm<<<grid, 256, 0, stream>>>(x, w_qkv, b_qkv, Qhi, Qlo, Khi, Klo, Vhi, Vlo);
    }
    {
        dim3 grid(1024);                   // 64 q-chunks x 16 bh (bh = bx & 15)
        attn_split<<<grid, 256, 0, stream>>>(Qhi, Qlo, Khi, Klo, Vhi, Vlo, AO);
    }
    {
        dim3 grid(MROWS / BM, CDIM / BN);  // 128 x 4
        proj_gemm<<<grid, 256, 0, stream>>>(AO, w_proj, b_proj, out);
    }
}

// Round 5
// 245.049 us; speedup vs baseline: 1.4950x; 1.2921x over previous
//
#include <hip/hip_runtime.h>
#include <math.h>

#define BATCH 2
#define NTOK 4096        // H*W
#define CDIM 256
#define NH 8
#define HD 32
#define MROWS (BATCH * NTOK)   // 8192

typedef __attribute__((ext_vector_type(8))) short bf16x8;
typedef __attribute__((ext_vector_type(4))) float f32x4;
typedef __attribute__((ext_vector_type(4))) unsigned u32x4;

union frag_u { uint4 q; u32x4 u; bf16x8 b; };

__device__ __forceinline__ unsigned short f2bf(float f) {
    union { float f; unsigned u; } x; x.f = f;
    unsigned r = x.u + 0x7FFFu + ((x.u >> 16) & 1u);   // RNE
    return (unsigned short)(r >> 16);
}
__device__ __forceinline__ float bf2f(unsigned short h) {
    union { unsigned u; float f; } x; x.u = ((unsigned)h) << 16; return x.f;
}
__device__ __forceinline__ float exp2_fast(float x) {
    float r;
    asm("v_exp_f32 %0, %1\n\ts_nop 0" : "=v"(r) : "v"(x));   // proven r2-r4
    return r;
}
__device__ __forceinline__ unsigned cvt_pk_bf16(float a, float b) {
    unsigned r;   // lo16 = bf16(a), hi16 = bf16(b), RNE
    asm("v_cvt_pk_bf16_f32 %0, %1, %2" : "=v"(r) : "v"(a), "v"(b));
    return r;
}
// C-frag dword pair (tile 2ks, tile 2ks+1) -> B-frag dword pair (w0, w1); proven r3/r4
__device__ __forceinline__ void permlane_pv(unsigned &a, unsigned &b) {
    asm("s_nop 1\n\t"
        "v_permlane32_swap_b32 %0, %1\n\t"
        "s_nop 1\n\t"
        "v_permlane16_swap_b32 %0, %1" : "+v"(a), "+v"(b));
}

// ---------------- QKV projection GEMM (unchanged, working) ----------------
#define BM 64
#define BN 64
#define BK 64

__global__ __launch_bounds__(256) void qkv_gemm(
    const float* __restrict__ X, const float* __restrict__ W,
    const float* __restrict__ bias,
    unsigned short* __restrict__ Qhi, unsigned short* __restrict__ Qlo,
    unsigned short* __restrict__ Khi, unsigned short* __restrict__ Klo,
    unsigned short* __restrict__ Vhi, unsigned short* __restrict__ Vlo)
{
    __shared__ float As[BK][BM + 4];
    __shared__ float Bs[BK][BN + 4];

    const int tid = threadIdx.x;
    const int tx = tid & 15;
    const int ty = tid >> 4;
    const int row0 = blockIdx.x * BM;
    const int col0 = blockIdx.y * BN;

    float c[4][4] = {};

    for (int k0 = 0; k0 < CDIM; k0 += BK) {
        #pragma unroll
        for (int i = 0; i < 4; ++i) {
            int l = tid + i * 256;
            int r = l >> 4;
            int k4 = (l & 15) << 2;
            float4 v = *(const float4*)&X[(size_t)(row0 + r) * CDIM + k0 + k4];
            As[k4 + 0][r] = v.x; As[k4 + 1][r] = v.y;
            As[k4 + 2][r] = v.z; As[k4 + 3][r] = v.w;
        }
        #pragma unroll
        for (int i = 0; i < 4; ++i) {
            int l = tid + i * 256;
            int r = l >> 4;
            int c4 = (l & 15) << 2;
            *(float4*)&Bs[r][c4] = *(const float4*)&W[(size_t)(k0 + r) * 768 + col0 + c4];
        }
        __syncthreads();

        #pragma unroll 16
        for (int kk = 0; kk < BK; ++kk) {
            float4 a = *(const float4*)&As[kk][ty << 2];
            float4 b = *(const float4*)&Bs[kk][tx << 2];
            float av[4] = {a.x, a.y, a.z, a.w};
            float bv[4] = {b.x, b.y, b.z, b.w};
            #pragma unroll
            for (int i = 0; i < 4; ++i)
                #pragma unroll
                for (int j = 0; j < 4; ++j)
                    c[i][j] = fmaf(av[i], bv[j], c[i][j]);
        }
        __syncthreads();
    }

    const int s = col0 >> 8;            // 0=Q 1=K 2=V
    const int b_ = row0 >> 12;
    const int n0 = (row0 & (NTOK - 1)) + (ty << 2);
    const int gc0 = col0 + (tx << 2);
    const int h  = (gc0 >> 5) & 7;
    const int e0 = gc0 & 31;
    const int bh = b_ * NH + h;
    // scale/sqrt(hd) * log2(e): QK^T lands directly in log2 domain
    const float QSC = (float)(1.4426950408889634 / 5.656854249492381);

    if (s == 0) {
        #pragma unroll
        for (int i = 0; i < 4; ++i) {
            unsigned short hh[4], ll[4];
            #pragma unroll
            for (int j = 0; j < 4; ++j) {
                float v = (c[i][j] + bias[gc0 + j]) * QSC;
                hh[j] = f2bf(v);
                ll[j] = f2bf(v - bf2f(hh[j]));
            }
            size_t idx = ((size_t)bh * NTOK + n0 + i) * HD + e0;
            uint2 hw; hw.x = hh[0] | ((unsigned)hh[1] << 16); hw.y = hh[2] | ((unsigned)hh[3] << 16);
            uint2 lw; lw.x = ll[0] | ((unsigned)ll[1] << 16); lw.y = ll[2] | ((unsigned)ll[3] << 16);
            *(uint2*)&Qhi[idx] = hw;
            *(uint2*)&Qlo[idx] = lw;
        }
    } else if (s == 1) {
        #pragma unroll
        for (int i = 0; i < 4; ++i) {
            unsigned short hh[4], ll[4];
            #pragma unroll
            for (int j = 0; j < 4; ++j) {
                float v = c[i][j] + bias[gc0 + j];
                hh[j] = f2bf(v);
                ll[j] = f2bf(v - bf2f(hh[j]));
            }
            size_t idx = ((size_t)bh * NTOK + n0 + i) * HD + e0;
            uint2 hw; hw.x = hh[0] | ((unsigned)hh[1] << 16); hw.y = hh[2] | ((unsigned)hh[3] << 16);
            uint2 lw; lw.x = ll[0] | ((unsigned)ll[1] << 16); lw.y = ll[2] | ((unsigned)ll[3] << 16);
            *(uint2*)&Khi[idx] = hw;
            *(uint2*)&Klo[idx] = lw;
        }
    } else {
        // V transposed: [bh][e][n]
        #pragma unroll
        for (int j = 0; j < 4; ++j) {
            unsigned short hh[4], ll[4];
            #pragma unroll
            for (int i = 0; i < 4; ++i) {
                float v = c[i][j] + bias[gc0 + j];
                hh[i] = f2bf(v);
                ll[i] = f2bf(v - bf2f(hh[i]));
            }
            size_t idx = ((size_t)bh * HD + e0 + j) * NTOK + n0;
            uint2 hw; hw.x = hh[0] | ((unsigned)hh[1] << 16); hw.y = hh[2] | ((unsigned)hh[3] << 16);
            uint2 lw; lw.x = ll[0] | ((unsigned)ll[1] << 16); lw.y = ll[2] | ((unsigned)ll[3] << 16);
            *(uint2*)&Vhi[idx] = hw;
            *(uint2*)&Vlo[idx] = lw;
        }
    }
}

// ---------------- MFMA flash attention: LDS-K double-buffer, direct-L2 V ----------------
// Block = 4 waves x 32 q-rows = 128 q-rows, full kv sweep (64 steps x 64 kv).
// K tile staged in LDS (double-buffered, reg-prefetch issued at step start ->
// whole compute phase hides global latency; ONE barrier per step). V fragments
// loaded per-lane straight from L2 (issued early, consumed after QK+softmax;
// 8 chunks/row = full 128B line -> L1 coalesces). No kv-split, no merge.
// Math identical to r4: 3-term QK, single-bf16 P (cvt_pk + permlane), 2-term V.
__global__ __launch_bounds__(256, 2) void attn_lds(
    const unsigned short* __restrict__ Qhi, const unsigned short* __restrict__ Qlo,
    const unsigned short* __restrict__ Khi, const unsigned short* __restrict__ Klo,
    const unsigned short* __restrict__ Vhi, const unsigned short* __restrict__ Vlo,
    float* __restrict__ AO)
{
    __shared__ __align__(16) unsigned short KH[2][64][40];   // pitch 80B (proven low-conflict)
    __shared__ __align__(16) unsigned short KL[2][64][40];

    const int tid = threadIdx.x;
    const int w = tid >> 6, lane = tid & 63, lq = lane & 15, g = lane >> 4;
    const int bx = blockIdx.x;
    const int bh = bx & 15, qc = bx >> 4;     // same-head blocks share XCD L2
    const int q0 = qc * 128 + w * 32;
    const size_t kb = (size_t)bh * (NTOK * HD);
    const size_t vb = (size_t)bh * (HD * NTOK);

    // ---- Q fragments (pre-scaled by scale*log2e) ----
    bf16x8 qh[2], qlo[2];
    #pragma unroll
    for (int qt = 0; qt < 2; ++qt) {
        size_t qi = kb + (size_t)(q0 + qt * 16 + lq) * HD + g * 8;
        qh[qt]  = *(const bf16x8*)(Qhi + qi);
        qlo[qt] = *(const bf16x8*)(Qlo + qi);
    }

    // ---- K staging: thread -> (row, 16B chunk); one uint4 each for hi/lo ----
    const int sr  = tid >> 2;            // 0..63
    const int sc8 = (tid & 3) << 3;      // 0,8,16,24 (shorts)
    const size_t gK = kb + (size_t)sr * HD + sc8;

    {   // prologue: stage step-0 K tile into LDS buffer 0
        uint4 h0 = *(const uint4*)(Khi + gK);
        uint4 l0 = *(const uint4*)(Klo + gK);
        *(uint4*)&KH[0][sr][sc8] = h0;
        *(uint4*)&KL[0][sr][sc8] = l0;
    }
    __syncthreads();

    // ---- V fragment bases (per-lane, direct from global/L2) ----
    size_t vbase[2][2];
    #pragma unroll
    for (int mt = 0; mt < 2; ++mt)
        #pragma unroll
        for (int ks = 0; ks < 2; ++ks)
            vbase[mt][ks] = vb + (size_t)(16 * mt + lq) * NTOK + ks * 32 + g * 8;

    f32x4 o[2][2] = {};
    f32x4 lacc[2] = {};
    float m_[2] = {-1e30f, -1e30f};

    for (int step = 0; step < 64; ++step) {
        const int cur = step & 1;

        // issue next-step K loads (landing time: end of this step's compute)
        // step-63 overrun reads the next head / Klo start -- in-workspace, unused.
        const size_t knext = gK + (size_t)(step + 1) * (64 * HD);
        uint4 nH = *(const uint4*)(Khi + knext);
        uint4 nL = *(const uint4*)(Klo + knext);

        // issue V fragment loads for this step (consumed after QK + softmax)
        frag_u vh[2][2], vl[2][2];
        {
            const int vo = step * 64;
            #pragma unroll
            for (int mt = 0; mt < 2; ++mt)
                #pragma unroll
                for (int ks = 0; ks < 2; ++ks) {
                    vh[mt][ks].q = *(const uint4*)(Vhi + vbase[mt][ks] + vo);
                    vl[mt][ks].q = *(const uint4*)(Vlo + vbase[mt][ks] + vo);
                }
        }

        // K fragments from LDS (current buffer)
        bf16x8 kh[4], kl[4];
        #pragma unroll
        for (int t = 0; t < 4; ++t) {
            kh[t] = *(const bf16x8*)&KH[cur][16 * t + lq][g * 8];
            kl[t] = *(const bf16x8*)&KL[cur][16 * t + lq][g * 8];
        }

        #pragma unroll
        for (int qt = 0; qt < 2; ++qt) {
            // QK^T (3-term split)
            f32x4 sc[4];
            #pragma unroll
            for (int t = 0; t < 4; ++t) {
                f32x4 cc = {0.f, 0.f, 0.f, 0.f};
                cc = __builtin_amdgcn_mfma_f32_16x16x32_bf16(kh[t], qh[qt],  cc, 0, 0, 0);
                cc = __builtin_amdgcn_mfma_f32_16x16x32_bf16(kh[t], qlo[qt], cc, 0, 0, 0);
                cc = __builtin_amdgcn_mfma_f32_16x16x32_bf16(kl[t], qh[qt],  cc, 0, 0, 0);
                sc[t] = cc;
            }
            // row max (per q-column lq)
            float mx = fmaxf(
                fmaxf(fmaxf(fmaxf(sc[0][0], sc[0][1]), fmaxf(sc[0][2], sc[0][3])),
                      fmaxf(fmaxf(sc[1][0], sc[1][1]), fmaxf(sc[1][2], sc[1][3]))),
                fmaxf(fmaxf(fmaxf(sc[2][0], sc[2][1]), fmaxf(sc[2][2], sc[2][3])),
                      fmaxf(fmaxf(sc[3][0], sc[3][1]), fmaxf(sc[3][2], sc[3][3]))));
            mx = fmaxf(mx, __shfl_xor(mx, 16));
            mx = fmaxf(mx, __shfl_xor(mx, 32));
            mx = fmaxf(mx, m_[qt]);
            float rs = exp2_fast(m_[qt] - mx);
            m_[qt] = mx;
            lacc[qt] *= rs;
            o[qt][0] *= rs;
            o[qt][1] *= rs;
            // P = exp2(s - m), single bf16
            unsigned ph[4][2];
            #pragma unroll
            for (int t = 0; t < 4; ++t) {
                float p0 = exp2_fast(sc[t][0] - mx);
                float p1 = exp2_fast(sc[t][1] - mx);
                float p2 = exp2_fast(sc[t][2] - mx);
                float p3 = exp2_fast(sc[t][3] - mx);
                lacc[qt] += (f32x4){p0, p1, p2, p3};
                ph[t][0] = cvt_pk_bf16(p0, p1);
                ph[t][1] = cvt_pk_bf16(p2, p3);
            }
            // PV: redistribute P (C-frag -> B-frag), accumulate O^T
            #pragma unroll
            for (int ks = 0; ks < 2; ++ks) {
                unsigned h00 = ph[2 * ks][0], h10 = ph[2 * ks + 1][0];
                unsigned h01 = ph[2 * ks][1], h11 = ph[2 * ks + 1][1];
                permlane_pv(h00, h10);
                permlane_pv(h01, h11);
                frag_u PH; PH.u = (u32x4){h00, h01, h10, h11};
                #pragma unroll
                for (int mt = 0; mt < 2; ++mt) {
                    o[qt][mt] = __builtin_amdgcn_mfma_f32_16x16x32_bf16(vh[mt][ks].b, PH.b, o[qt][mt], 0, 0, 0);
                    o[qt][mt] = __builtin_amdgcn_mfma_f32_16x16x32_bf16(vl[mt][ks].b, PH.b, o[qt][mt], 0, 0, 0);
                }
            }
        }

        // write prefetched K tile into the other buffer; one barrier per step
        *(uint4*)&KH[cur ^ 1][sr][sc8] = nH;
        *(uint4*)&KL[cur ^ 1][sr][sc8] = nL;
        __syncthreads();
    }

    // ---- finalize: reduce l across g-groups, scale, store ----
    const int b_ = bh >> 3, h_ = bh & 7;
    #pragma unroll
    for (int qt = 0; qt < 2; ++qt) {
        float ls = (lacc[qt][0] + lacc[qt][1]) + (lacc[qt][2] + lacc[qt][3]);
        ls += __shfl_xor(ls, 16);
        ls += __shfl_xor(ls, 32);
        float inv = 1.0f / ls;
        int qg = q0 + qt * 16 + lq;
        #pragma unroll
        for (int mt = 0; mt < 2; ++mt) {
            float4 st;
            st.x = o[qt][mt][0] * inv;
            st.y = o[qt][mt][1] * inv;
            st.z = o[qt][mt][2] * inv;
            st.w = o[qt][mt][3] * inv;
            *(float4*)&AO[((size_t)b_ * NTOK + qg) * CDIM + h_ * 32 + mt * 16 + g * 4] = st;
        }
    }
}

// ---------------- Output projection GEMM (unchanged, working) ----------------
__global__ __launch_bounds__(256) void proj_gemm(
    const float* __restrict__ A, const float* __restrict__ W,
    const float* __restrict__ bias, float* __restrict__ out)
{
    __shared__ float As[BK][BM + 4];
    __shared__ float Bs[BK][BN + 4];

    const int tid = threadIdx.x;
    const int tx = tid & 15;
    const int ty = tid >> 4;
    const int row0 = blockIdx.x * BM;
    const int col0 = blockIdx.y * BN;

    float c[4][4] = {};

    for (int k0 = 0; k0 < CDIM; k0 += BK) {
        #pragma unroll
        for (int i = 0; i < 4; ++i) {
            int l = tid + i * 256;
            int r = l >> 4;
            int k4 = (l & 15) << 2;
            float4 v = *(const float4*)&A[(size_t)(row0 + r) * CDIM + k0 + k4];
            As[k4 + 0][r] = v.x; As[k4 + 1][r] = v.y;
            As[k4 + 2][r] = v.z; As[k4 + 3][r] = v.w;
        }
        #pragma unroll
        for (int i = 0; i < 4; ++i) {
            int l = tid + i * 256;
            int r = l >> 4;
            int c4 = (l & 15) << 2;
            *(float4*)&Bs[r][c4] = *(const float4*)&W[(size_t)(k0 + r) * CDIM + col0 + c4];
        }
        __syncthreads();

        #pragma unroll 16
        for (int kk = 0; kk < BK; ++kk) {
            float4 a = *(const float4*)&As[kk][ty << 2];
            float4 b = *(const float4*)&Bs[kk][tx << 2];
            float av[4] = {a.x, a.y, a.z, a.w};
            float bv[4] = {b.x, b.y, b.z, b.w};
            #pragma unroll
            for (int i = 0; i < 4; ++i)
                #pragma unroll
                for (int j = 0; j < 4; ++j)
                    c[i][j] = fmaf(av[i], bv[j], c[i][j]);
        }
        __syncthreads();
    }

    #pragma unroll
    for (int i = 0; i < 4; ++i) {
        int gr = row0 + (ty << 2) + i;
        #pragma unroll
        for (int j = 0; j < 4; ++j) {
            int gc = col0 + (tx << 2) + j;
            out[(size_t)gr * CDIM + gc] = c[i][j] + bias[gc];
        }
    }
}

extern "C" void kernel_launch(void* const* d_in, const int* in_sizes, int n_in,
                              void* d_out, int out_size, void* d_ws, size_t ws_size,
                              hipStream_t stream)
{
    const float* x      = (const float*)d_in[0];
    const float* w_qkv  = (const float*)d_in[1];
    const float* b_qkv  = (const float*)d_in[2];
    const float* w_proj = (const float*)d_in[3];
    const float* b_proj = (const float*)d_in[4];
    // d_in[5] rel_bias: per-head scalar over the full score matrix -> softmax no-op.

    float* out = (float*)d_out;

    // ws: Qhi|Qlo|Khi|Klo|Vhi|Vlo (4MB each, bf16) + AO (8MB f32) = 32MB
    const size_t NE = (size_t)BATCH * NH * NTOK * HD;   // 2,097,152
    char* p = (char*)d_ws;
    unsigned short* Qhi = (unsigned short*)p;  p += NE * 2;
    unsigned short* Qlo = (unsigned short*)p;  p += NE * 2;
    unsigned short* Khi = (unsigned short*)p;  p += NE * 2;
    unsigned short* Klo = (unsigned short*)p;  p += NE * 2;
    unsigned short* Vhi = (unsigned short*)p;  p += NE * 2;
    unsigned short* Vlo = (unsigned short*)p;  p += NE * 2;
    float* AO           = (float*)p;

    {
        dim3 grid(MROWS / BM, 768 / BN);   // 128 x 12
        qkv_gemm<<<grid, 256, 0, stream>>>(x, w_qkv, b_qkv, Qhi, Qlo, Khi, Klo, Vhi, Vlo);
    }
    {
        dim3 grid(512);                    // 32 q-chunks x 16 bh (bh = bx & 15)
        attn_lds<<<grid, 256, 0, stream>>>(Qhi, Qlo, Khi, Klo, Vhi, Vlo, AO);
    }
    {
        dim3 grid(MROWS / BM, CDIM / BN);  // 128 x 4
        proj_gemm<<<grid, 256, 0, stream>>>(AO, w_proj, b_proj, out);
    }
}

// Round 6
// 211.522 us; speedup vs baseline: 1.7320x; 1.1585x over previous
//
#include <hip/hip_runtime.h>
#include <math.h>

#define BATCH 2
#define NTOK 4096        // H*W
#define CDIM 256
#define NH 8
#define HD 32
#define MROWS (BATCH * NTOK)   // 8192

typedef __attribute__((ext_vector_type(8))) short bf16x8;
typedef __attribute__((ext_vector_type(4))) float f32x4;
typedef __attribute__((ext_vector_type(4))) unsigned u32x4;

union frag_u { uint4 q; u32x4 u; bf16x8 b; };

__device__ __forceinline__ unsigned short f2bf(float f) {
    union { float f; unsigned u; } x; x.f = f;
    unsigned r = x.u + 0x7FFFu + ((x.u >> 16) & 1u);   // RNE
    return (unsigned short)(r >> 16);
}
__device__ __forceinline__ float bf2f(unsigned short h) {
    union { unsigned u; float f; } x; x.u = ((unsigned)h) << 16; return x.f;
}
__device__ __forceinline__ float exp2_fast(float x) {
    float r;
    asm("v_exp_f32 %0, %1\n\ts_nop 0" : "=v"(r) : "v"(x));   // proven r2-r5
    return r;
}
__device__ __forceinline__ unsigned cvt_pk_bf16(float a, float b) {
    unsigned r;   // lo16 = bf16(a), hi16 = bf16(b), RNE
    asm("v_cvt_pk_bf16_f32 %0, %1, %2" : "=v"(r) : "v"(a), "v"(b));
    return r;
}
// C-frag dword pair (tile 2ks, tile 2ks+1) -> B-frag dword pair (w0, w1); proven r3-r5
__device__ __forceinline__ void permlane_pv(unsigned &a, unsigned &b) {
    asm("s_nop 1\n\t"
        "v_permlane32_swap_b32 %0, %1\n\t"
        "s_nop 1\n\t"
        "v_permlane16_swap_b32 %0, %1" : "+v"(a), "+v"(b));
}

// ---------------- QKV projection GEMM (unchanged, working) ----------------
#define BM 64
#define BN 64
#define BK 64

__global__ __launch_bounds__(256) void qkv_gemm(
    const float* __restrict__ X, const float* __restrict__ W,
    const float* __restrict__ bias,
    unsigned short* __restrict__ Qhi, unsigned short* __restrict__ Qlo,
    unsigned short* __restrict__ Khi, unsigned short* __restrict__ Klo,
    unsigned short* __restrict__ Vhi, unsigned short* __restrict__ Vlo)
{
    __shared__ float As[BK][BM + 4];
    __shared__ float Bs[BK][BN + 4];

    const int tid = threadIdx.x;
    const int tx = tid & 15;
    const int ty = tid >> 4;
    const int row0 = blockIdx.x * BM;
    const int col0 = blockIdx.y * BN;

    float c[4][4] = {};

    for (int k0 = 0; k0 < CDIM; k0 += BK) {
        #pragma unroll
        for (int i = 0; i < 4; ++i) {
            int l = tid + i * 256;
            int r = l >> 4;
            int k4 = (l & 15) << 2;
            float4 v = *(const float4*)&X[(size_t)(row0 + r) * CDIM + k0 + k4];
            As[k4 + 0][r] = v.x; As[k4 + 1][r] = v.y;
            As[k4 + 2][r] = v.z; As[k4 + 3][r] = v.w;
        }
        #pragma unroll
        for (int i = 0; i < 4; ++i) {
            int l = tid + i * 256;
            int r = l >> 4;
            int c4 = (l & 15) << 2;
            *(float4*)&Bs[r][c4] = *(const float4*)&W[(size_t)(k0 + r) * 768 + col0 + c4];
        }
        __syncthreads();

        #pragma unroll 16
        for (int kk = 0; kk < BK; ++kk) {
            float4 a = *(const float4*)&As[kk][ty << 2];
            float4 b = *(const float4*)&Bs[kk][tx << 2];
            float av[4] = {a.x, a.y, a.z, a.w};
            float bv[4] = {b.x, b.y, b.z, b.w};
            #pragma unroll
            for (int i = 0; i < 4; ++i)
                #pragma unroll
                for (int j = 0; j < 4; ++j)
                    c[i][j] = fmaf(av[i], bv[j], c[i][j]);
        }
        __syncthreads();
    }

    const int s = col0 >> 8;            // 0=Q 1=K 2=V
    const int b_ = row0 >> 12;
    const int n0 = (row0 & (NTOK - 1)) + (ty << 2);
    const int gc0 = col0 + (tx << 2);
    const int h  = (gc0 >> 5) & 7;
    const int e0 = gc0 & 31;
    const int bh = b_ * NH + h;
    // scale/sqrt(hd) * log2(e): QK^T lands directly in log2 domain
    const float QSC = (float)(1.4426950408889634 / 5.656854249492381);

    if (s == 0) {
        #pragma unroll
        for (int i = 0; i < 4; ++i) {
            unsigned short hh[4], ll[4];
            #pragma unroll
            for (int j = 0; j < 4; ++j) {
                float v = (c[i][j] + bias[gc0 + j]) * QSC;
                hh[j] = f2bf(v);
                ll[j] = f2bf(v - bf2f(hh[j]));
            }
            size_t idx = ((size_t)bh * NTOK + n0 + i) * HD + e0;
            uint2 hw; hw.x = hh[0] | ((unsigned)hh[1] << 16); hw.y = hh[2] | ((unsigned)hh[3] << 16);
            uint2 lw; lw.x = ll[0] | ((unsigned)ll[1] << 16); lw.y = ll[2] | ((unsigned)ll[3] << 16);
            *(uint2*)&Qhi[idx] = hw;
            *(uint2*)&Qlo[idx] = lw;
        }
    } else if (s == 1) {
        #pragma unroll
        for (int i = 0; i < 4; ++i) {
            unsigned short hh[4], ll[4];
            #pragma unroll
            for (int j = 0; j < 4; ++j) {
                float v = c[i][j] + bias[gc0 + j];
                hh[j] = f2bf(v);
                ll[j] = f2bf(v - bf2f(hh[j]));
            }
            size_t idx = ((size_t)bh * NTOK + n0 + i) * HD + e0;
            uint2 hw; hw.x = hh[0] | ((unsigned)hh[1] << 16); hw.y = hh[2] | ((unsigned)hh[3] << 16);
            uint2 lw; lw.x = ll[0] | ((unsigned)ll[1] << 16); lw.y = ll[2] | ((unsigned)ll[3] << 16);
            *(uint2*)&Khi[idx] = hw;
            *(uint2*)&Klo[idx] = lw;
        }
    } else {
        // V transposed: [bh][e][n]
        #pragma unroll
        for (int j = 0; j < 4; ++j) {
            unsigned short hh[4], ll[4];
            #pragma unroll
            for (int i = 0; i < 4; ++i) {
                float v = c[i][j] + bias[gc0 + j];
                hh[i] = f2bf(v);
                ll[i] = f2bf(v - bf2f(hh[i]));
            }
            size_t idx = ((size_t)bh * HD + e0 + j) * NTOK + n0;
            uint2 hw; hw.x = hh[0] | ((unsigned)hh[1] << 16); hw.y = hh[2] | ((unsigned)hh[3] << 16);
            uint2 lw; lw.x = ll[0] | ((unsigned)ll[1] << 16); lw.y = ll[2] | ((unsigned)ll[3] << 16);
            *(uint2*)&Vhi[idx] = hw;
            *(uint2*)&Vlo[idx] = lw;
        }
    }
}

// ---------------- MFMA flash attention v6: 16 q-rows/wave, K+V in LDS ----------------
// Block = 4 waves x 16 q-rows = 64 q-rows; grid = 64 q-chunks x 16 bh = 1024
// blocks -> 4 blocks/CU, target 16 waves/CU (50% occ) at VGPR<=128.
// K+V single-buffered in LDS; step s+1 prefetched into regs right after the
// visibility barrier (full compute phase covers L2 latency; pre-write vmcnt
// waits on loads issued one whole step earlier). Two barriers per step.
// All global offsets 32-bit. Math identical to r5 (3-term QK, single-bf16 P
// via cvt_pk+permlane, 2-term PV, exp2 domain).
__global__ __launch_bounds__(256, 3) void attn_v6(
    const unsigned short* __restrict__ Qhi, const unsigned short* __restrict__ Qlo,
    const unsigned short* __restrict__ Khi, const unsigned short* __restrict__ Klo,
    const unsigned short* __restrict__ Vhi, const unsigned short* __restrict__ Vlo,
    float* __restrict__ AO)
{
    __shared__ __align__(16) unsigned short KH[64][44], KL[64][44];   // pitch 88B
    __shared__ __align__(16) unsigned short VH[32][72], VL[32][72];   // pitch 144B

    const int tid = threadIdx.x;
    const int w = tid >> 6, lane = tid & 63, lq = lane & 15, g = lane >> 4;
    const int bx = blockIdx.x;
    const int bh = bx & 15, qc = bx >> 4;     // same-head blocks share XCD L2
    const int q0 = qc * 64 + w * 16;
    const int kb = bh * (NTOK * HD);          // fits 32-bit (max 2M)
    const int vb = bh * (HD * NTOK);

    // ---- Q fragment (pre-scaled by scale*log2e) ----
    bf16x8 qh, ql;
    {
        const int qi = kb + (q0 + lq) * HD + g * 8;
        qh = *(const bf16x8*)(Qhi + qi);
        ql = *(const bf16x8*)(Qlo + qi);
    }

    // ---- staging slots: K row 0..63 / 16B chunk; V row 0..31 / 16B chunk ----
    const int kr = tid >> 2, kc = (tid & 3) << 3;
    const int vr = tid >> 3, vc = (tid & 7) << 3;
    const int kgbase = kb + kr * HD + kc;
    const int vgbase = vb + vr * NTOK + vc;

    // prologue: load step-0 tiles into regs
    uint4 sKH = *(const uint4*)(Khi + kgbase);
    uint4 sKL = *(const uint4*)(Klo + kgbase);
    uint4 sVH = *(const uint4*)(Vhi + vgbase);
    uint4 sVL = *(const uint4*)(Vlo + vgbase);

    f32x4 o0 = {}, o1 = {};
    f32x4 lacc = {};
    float m_ = -1e30f;

    for (int step = 0; step < 64; ++step) {
        __syncthreads();                     // prev compute done: LDS overwritable
        *(uint4*)&KH[kr][kc] = sKH;          // implicit vmcnt wait (loads issued
        *(uint4*)&KL[kr][kc] = sKL;          //  one full step ago)
        *(uint4*)&VH[vr][vc] = sVH;
        *(uint4*)&VL[vr][vc] = sVL;
        __syncthreads();                     // tile visible

        // issue next-step loads now; land during this step's compute
        {
            const int nx = ((step + 1) & 63) * 64;   // wrap: reads valid, unused
            sKH = *(const uint4*)(Khi + kgbase + nx * HD);
            sKL = *(const uint4*)(Klo + kgbase + nx * HD);
            sVH = *(const uint4*)(Vhi + vgbase + nx);
            sVL = *(const uint4*)(Vlo + vgbase + nx);
        }

        // ---- K fragments from LDS ----
        bf16x8 kh[4], kl[4];
        #pragma unroll
        for (int t = 0; t < 4; ++t) {
            kh[t] = *(const bf16x8*)&KH[16 * t + lq][g * 8];
            kl[t] = *(const bf16x8*)&KL[16 * t + lq][g * 8];
        }

        // ---- QK^T (3-term split) ----
        f32x4 sc[4];
        #pragma unroll
        for (int t = 0; t < 4; ++t) {
            f32x4 cc = {0.f, 0.f, 0.f, 0.f};
            cc = __builtin_amdgcn_mfma_f32_16x16x32_bf16(kh[t], qh, cc, 0, 0, 0);
            cc = __builtin_amdgcn_mfma_f32_16x16x32_bf16(kh[t], ql, cc, 0, 0, 0);
            cc = __builtin_amdgcn_mfma_f32_16x16x32_bf16(kl[t], qh, cc, 0, 0, 0);
            sc[t] = cc;
        }

        // ---- online softmax ----
        float mx = fmaxf(
            fmaxf(fmaxf(fmaxf(sc[0][0], sc[0][1]), fmaxf(sc[0][2], sc[0][3])),
                  fmaxf(fmaxf(sc[1][0], sc[1][1]), fmaxf(sc[1][2], sc[1][3]))),
            fmaxf(fmaxf(fmaxf(sc[2][0], sc[2][1]), fmaxf(sc[2][2], sc[2][3])),
                  fmaxf(fmaxf(sc[3][0], sc[3][1]), fmaxf(sc[3][2], sc[3][3]))));
        mx = fmaxf(mx, __shfl_xor(mx, 16));
        mx = fmaxf(mx, __shfl_xor(mx, 32));
        mx = fmaxf(mx, m_);
        float rs = exp2_fast(m_ - mx);
        m_ = mx;
        lacc *= rs;
        o0 *= rs;
        o1 *= rs;

        unsigned ph[4][2];
        #pragma unroll
        for (int t = 0; t < 4; ++t) {
            float p0 = exp2_fast(sc[t][0] - mx);
            float p1 = exp2_fast(sc[t][1] - mx);
            float p2 = exp2_fast(sc[t][2] - mx);
            float p3 = exp2_fast(sc[t][3] - mx);
            lacc += (f32x4){p0, p1, p2, p3};
            ph[t][0] = cvt_pk_bf16(p0, p1);
            ph[t][1] = cvt_pk_bf16(p2, p3);
        }

        // ---- PV: redistribute P (C-frag -> B-frag), lazy V frags from LDS ----
        #pragma unroll
        for (int ks = 0; ks < 2; ++ks) {
            unsigned h00 = ph[2 * ks][0], h10 = ph[2 * ks + 1][0];
            unsigned h01 = ph[2 * ks][1], h11 = ph[2 * ks + 1][1];
            permlane_pv(h00, h10);
            permlane_pv(h01, h11);
            frag_u PH; PH.u = (u32x4){h00, h01, h10, h11};
            {
                bf16x8 vhf = *(const bf16x8*)&VH[lq][ks * 32 + g * 8];
                bf16x8 vlf = *(const bf16x8*)&VL[lq][ks * 32 + g * 8];
                o0 = __builtin_amdgcn_mfma_f32_16x16x32_bf16(vhf, PH.b, o0, 0, 0, 0);
                o0 = __builtin_amdgcn_mfma_f32_16x16x32_bf16(vlf, PH.b, o0, 0, 0, 0);
            }
            {
                bf16x8 vhf = *(const bf16x8*)&VH[16 + lq][ks * 32 + g * 8];
                bf16x8 vlf = *(const bf16x8*)&VL[16 + lq][ks * 32 + g * 8];
                o1 = __builtin_amdgcn_mfma_f32_16x16x32_bf16(vhf, PH.b, o1, 0, 0, 0);
                o1 = __builtin_amdgcn_mfma_f32_16x16x32_bf16(vlf, PH.b, o1, 0, 0, 0);
            }
        }
    }

    // ---- finalize: reduce l across g-groups, scale, store ----
    const int b_ = bh >> 3, h_ = bh & 7;
    float ls = (lacc[0] + lacc[1]) + (lacc[2] + lacc[3]);
    ls += __shfl_xor(ls, 16);
    ls += __shfl_xor(ls, 32);
    const float inv = 1.0f / ls;
    const int qg = q0 + lq;
    {
        float4 st;
        st.x = o0[0] * inv; st.y = o0[1] * inv;
        st.z = o0[2] * inv; st.w = o0[3] * inv;
        *(float4*)&AO[((size_t)b_ * NTOK + qg) * CDIM + h_ * 32 + g * 4] = st;
    }
    {
        float4 st;
        st.x = o1[0] * inv; st.y = o1[1] * inv;
        st.z = o1[2] * inv; st.w = o1[3] * inv;
        *(float4*)&AO[((size_t)b_ * NTOK + qg) * CDIM + h_ * 32 + 16 + g * 4] = st;
    }
}

// ---------------- Output projection GEMM (unchanged, working) ----------------
__global__ __launch_bounds__(256) void proj_gemm(
    const float* __restrict__ A, const float* __restrict__ W,
    const float* __restrict__ bias, float* __restrict__ out)
{
    __shared__ float As[BK][BM + 4];
    __shared__ float Bs[BK][BN + 4];

    const int tid = threadIdx.x;
    const int tx = tid & 15;
    const int ty = tid >> 4;
    const int row0 = blockIdx.x * BM;
    const int col0 = blockIdx.y * BN;

    float c[4][4] = {};

    for (int k0 = 0; k0 < CDIM; k0 += BK) {
        #pragma unroll
        for (int i = 0; i < 4; ++i) {
            int l = tid + i * 256;
            int r = l >> 4;
            int k4 = (l & 15) << 2;
            float4 v = *(const float4*)&A[(size_t)(row0 + r) * CDIM + k0 + k4];
            As[k4 + 0][r] = v.x; As[k4 + 1][r] = v.y;
            As[k4 + 2][r] = v.z; As[k4 + 3][r] = v.w;
        }
        #pragma unroll
        for (int i = 0; i < 4; ++i) {
            int l = tid + i * 256;
            int r = l >> 4;
            int c4 = (l & 15) << 2;
            *(float4*)&Bs[r][c4] = *(const float4*)&W[(size_t)(k0 + r) * CDIM + col0 + c4];
        }
        __syncthreads();

        #pragma unroll 16
        for (int kk = 0; kk < BK; ++kk) {
            float4 a = *(const float4*)&As[kk][ty << 2];
            float4 b = *(const float4*)&Bs[kk][tx << 2];
            float av[4] = {a.x, a.y, a.z, a.w};
            float bv[4] = {b.x, b.y, b.z, b.w};
            #pragma unroll
            for (int i = 0; i < 4; ++i)
                #pragma unroll
                for (int j = 0; j < 4; ++j)
                    c[i][j] = fmaf(av[i], bv[j], c[i][j]);
        }
        __syncthreads();
    }

    #pragma unroll
    for (int i = 0; i < 4; ++i) {
        int gr = row0 + (ty << 2) + i;
        #pragma unroll
        for (int j = 0; j < 4; ++j) {
            int gc = col0 + (tx << 2) + j;
            out[(size_t)gr * CDIM + gc] = c[i][j] + bias[gc];
        }
    }
}

extern "C" void kernel_launch(void* const* d_in, const int* in_sizes, int n_in,
                              void* d_out, int out_size, void* d_ws, size_t ws_size,
                              hipStream_t stream)
{
    const float* x      = (const float*)d_in[0];
    const float* w_qkv  = (const float*)d_in[1];
    const float* b_qkv  = (const float*)d_in[2];
    const float* w_proj = (const float*)d_in[3];
    const float* b_proj = (const float*)d_in[4];
    // d_in[5] rel_bias: per-head scalar over the full score matrix -> softmax no-op.

    float* out = (float*)d_out;

    // ws: Qhi|Qlo|Khi|Klo|Vhi|Vlo (4MB each, bf16) + AO (8MB f32) = 32MB
    const size_t NE = (size_t)BATCH * NH * NTOK * HD;   // 2,097,152
    char* p = (char*)d_ws;
    unsigned short* Qhi = (unsigned short*)p;  p += NE * 2;
    unsigned short* Qlo = (unsigned short*)p;  p += NE * 2;
    unsigned short* Khi = (unsigned short*)p;  p += NE * 2;
    unsigned short* Klo = (unsigned short*)p;  p += NE * 2;
    unsigned short* Vhi = (unsigned short*)p;  p += NE * 2;
    unsigned short* Vlo = (unsigned short*)p;  p += NE * 2;
    float* AO           = (float*)p;

    {
        dim3 grid(MROWS / BM, 768 / BN);   // 128 x 12
        qkv_gemm<<<grid, 256, 0, stream>>>(x, w_qkv, b_qkv, Qhi, Qlo, Khi, Klo, Vhi, Vlo);
    }
    {
        dim3 grid(1024);                   // 64 q-chunks x 16 bh (bh = bx & 15)
        attn_v6<<<grid, 256, 0, stream>>>(Qhi, Qlo, Khi, Klo, Vhi, Vlo, AO);
    }
    {
        dim3 grid(MROWS / BM, CDIM / BN);  // 128 x 4
        proj_gemm<<<grid, 256, 0, stream>>>(AO, w_proj, b_proj, out);
    }
}

// Round 7
// 211.112 us; speedup vs baseline: 1.7353x; 1.0019x over previous
//
#include <hip/hip_runtime.h>
#include <math.h>

#define BATCH 2
#define NTOK 4096        // H*W
#define CDIM 256
#define NH 8
#define HD 32
#define MROWS (BATCH * NTOK)   // 8192

typedef __attribute__((ext_vector_type(8))) short bf16x8;
typedef __attribute__((ext_vector_type(4))) float f32x4;
typedef __attribute__((ext_vector_type(4))) unsigned u32x4;

union frag_u { uint4 q; u32x4 u; bf16x8 b; };

__device__ __forceinline__ unsigned short f2bf(float f) {
    union { float f; unsigned u; } x; x.f = f;
    unsigned r = x.u + 0x7FFFu + ((x.u >> 16) & 1u);   // RNE
    return (unsigned short)(r >> 16);
}
__device__ __forceinline__ float bf2f(unsigned short h) {
    union { unsigned u; float f; } x; x.u = ((unsigned)h) << 16; return x.f;
}
__device__ __forceinline__ float exp2_fast(float x) {
    float r;
    asm("v_exp_f32 %0, %1\n\ts_nop 0" : "=v"(r) : "v"(x));   // proven r2-r5
    return r;
}
__device__ __forceinline__ unsigned cvt_pk_bf16(float a, float b) {
    unsigned r;   // lo16 = bf16(a), hi16 = bf16(b), RNE
    asm("v_cvt_pk_bf16_f32 %0, %1, %2" : "=v"(r) : "v"(a), "v"(b));
    return r;
}
// C-frag dword pair (tile 2ks, tile 2ks+1) -> B-frag dword pair (w0, w1); proven r3-r5
__device__ __forceinline__ void permlane_pv(unsigned &a, unsigned &b) {
    asm("s_nop 1\n\t"
        "v_permlane32_swap_b32 %0, %1\n\t"
        "s_nop 1\n\t"
        "v_permlane16_swap_b32 %0, %1" : "+v"(a), "+v"(b));
}

// ---------------- QKV projection GEMM (unchanged, working) ----------------
#define BM 64
#define BN 64
#define BK 64

__global__ __launch_bounds__(256) void qkv_gemm(
    const float* __restrict__ X, const float* __restrict__ W,
    const float* __restrict__ bias,
    unsigned short* __restrict__ Qhi, unsigned short* __restrict__ Qlo,
    unsigned short* __restrict__ Khi, unsigned short* __restrict__ Klo,
    unsigned short* __restrict__ Vhi, unsigned short* __restrict__ Vlo)
{
    __shared__ float As[BK][BM + 4];
    __shared__ float Bs[BK][BN + 4];

    const int tid = threadIdx.x;
    const int tx = tid & 15;
    const int ty = tid >> 4;
    const int row0 = blockIdx.x * BM;
    const int col0 = blockIdx.y * BN;

    float c[4][4] = {};

    for (int k0 = 0; k0 < CDIM; k0 += BK) {
        #pragma unroll
        for (int i = 0; i < 4; ++i) {
            int l = tid + i * 256;
            int r = l >> 4;
            int k4 = (l & 15) << 2;
            float4 v = *(const float4*)&X[(size_t)(row0 + r) * CDIM + k0 + k4];
            As[k4 + 0][r] = v.x; As[k4 + 1][r] = v.y;
            As[k4 + 2][r] = v.z; As[k4 + 3][r] = v.w;
        }
        #pragma unroll
        for (int i = 0; i < 4; ++i) {
            int l = tid + i * 256;
            int r = l >> 4;
            int c4 = (l & 15) << 2;
            *(float4*)&Bs[r][c4] = *(const float4*)&W[(size_t)(k0 + r) * 768 + col0 + c4];
        }
        __syncthreads();

        #pragma unroll 16
        for (int kk = 0; kk < BK; ++kk) {
            float4 a = *(const float4*)&As[kk][ty << 2];
            float4 b = *(const float4*)&Bs[kk][tx << 2];
            float av[4] = {a.x, a.y, a.z, a.w};
            float bv[4] = {b.x, b.y, b.z, b.w};
            #pragma unroll
            for (int i = 0; i < 4; ++i)
                #pragma unroll
                for (int j = 0; j < 4; ++j)
                    c[i][j] = fmaf(av[i], bv[j], c[i][j]);
        }
        __syncthreads();
    }

    const int s = col0 >> 8;            // 0=Q 1=K 2=V
    const int b_ = row0 >> 12;
    const int n0 = (row0 & (NTOK - 1)) + (ty << 2);
    const int gc0 = col0 + (tx << 2);
    const int h  = (gc0 >> 5) & 7;
    const int e0 = gc0 & 31;
    const int bh = b_ * NH + h;
    // scale/sqrt(hd) * log2(e): QK^T lands directly in log2 domain
    const float QSC = (float)(1.4426950408889634 / 5.656854249492381);

    if (s == 0) {
        #pragma unroll
        for (int i = 0; i < 4; ++i) {
            unsigned short hh[4], ll[4];
            #pragma unroll
            for (int j = 0; j < 4; ++j) {
                float v = (c[i][j] + bias[gc0 + j]) * QSC;
                hh[j] = f2bf(v);
                ll[j] = f2bf(v - bf2f(hh[j]));
            }
            size_t idx = ((size_t)bh * NTOK + n0 + i) * HD + e0;
            uint2 hw; hw.x = hh[0] | ((unsigned)hh[1] << 16); hw.y = hh[2] | ((unsigned)hh[3] << 16);
            uint2 lw; lw.x = ll[0] | ((unsigned)ll[1] << 16); lw.y = ll[2] | ((unsigned)ll[3] << 16);
            *(uint2*)&Qhi[idx] = hw;
            *(uint2*)&Qlo[idx] = lw;
        }
    } else if (s == 1) {
        #pragma unroll
        for (int i = 0; i < 4; ++i) {
            unsigned short hh[4], ll[4];
            #pragma unroll
            for (int j = 0; j < 4; ++j) {
                float v = c[i][j] + bias[gc0 + j];
                hh[j] = f2bf(v);
                ll[j] = f2bf(v - bf2f(hh[j]));
            }
            size_t idx = ((size_t)bh * NTOK + n0 + i) * HD + e0;
            uint2 hw; hw.x = hh[0] | ((unsigned)hh[1] << 16); hw.y = hh[2] | ((unsigned)hh[3] << 16);
            uint2 lw; lw.x = ll[0] | ((unsigned)ll[1] << 16); lw.y = ll[2] | ((unsigned)ll[3] << 16);
            *(uint2*)&Khi[idx] = hw;
            *(uint2*)&Klo[idx] = lw;
        }
    } else {
        // V transposed: [bh][e][n]
        #pragma unroll
        for (int j = 0; j < 4; ++j) {
            unsigned short hh[4], ll[4];
            #pragma unroll
            for (int i = 0; i < 4; ++i) {
                float v = c[i][j] + bias[gc0 + j];
                hh[i] = f2bf(v);
                ll[i] = f2bf(v - bf2f(hh[i]));
            }
            size_t idx = ((size_t)bh * HD + e0 + j) * NTOK + n0;
            uint2 hw; hw.x = hh[0] | ((unsigned)hh[1] << 16); hw.y = hh[2] | ((unsigned)hh[3] << 16);
            uint2 lw; lw.x = ll[0] | ((unsigned)ll[1] << 16); lw.y = ll[2] | ((unsigned)ll[3] << 16);
            *(uint2*)&Vhi[idx] = hw;
            *(uint2*)&Vlo[idx] = lw;
        }
    }
}

// ---------------- MFMA flash attention v6: 16 q-rows/wave, K+V in LDS ----------------
// Block = 4 waves x 16 q-rows = 64 q-rows; grid = 64 q-chunks x 16 bh = 1024
// blocks -> 4 blocks/CU, target 16 waves/CU (50% occ) at VGPR<=128.
// K+V single-buffered in LDS; step s+1 prefetched into regs right after the
// visibility barrier (full compute phase covers L2 latency; pre-write vmcnt
// waits on loads issued one whole step earlier). Two barriers per step.
// All global offsets 32-bit. Math identical to r5 (3-term QK, single-bf16 P
// via cvt_pk+permlane, 2-term PV, exp2 domain).
__global__ __launch_bounds__(256, 3) void attn_v6(
    const unsigned short* __restrict__ Qhi, const unsigned short* __restrict__ Qlo,
    const unsigned short* __restrict__ Khi, const unsigned short* __restrict__ Klo,
    const unsigned short* __restrict__ Vhi, const unsigned short* __restrict__ Vlo,
    float* __restrict__ AO)
{
    __shared__ __align__(16) unsigned short KH[64][44], KL[64][44];   // pitch 88B
    __shared__ __align__(16) unsigned short VH[32][72], VL[32][72];   // pitch 144B

    const int tid = threadIdx.x;
    const int w = tid >> 6, lane = tid & 63, lq = lane & 15, g = lane >> 4;
    const int bx = blockIdx.x;
    const int bh = bx & 15, qc = bx >> 4;     // same-head blocks share XCD L2
    const int q0 = qc * 64 + w * 16;
    const int kb = bh * (NTOK * HD);          // fits 32-bit (max 2M)
    const int vb = bh * (HD * NTOK);

    // ---- Q fragment (pre-scaled by scale*log2e) ----
    bf16x8 qh, ql;
    {
        const int qi = kb + (q0 + lq) * HD + g * 8;
        qh = *(const bf16x8*)(Qhi + qi);
        ql = *(const bf16x8*)(Qlo + qi);
    }

    // ---- staging slots: K row 0..63 / 16B chunk; V row 0..31 / 16B chunk ----
    const int kr = tid >> 2, kc = (tid & 3) << 3;
    const int vr = tid >> 3, vc = (tid & 7) << 3;
    const int kgbase = kb + kr * HD + kc;
    const int vgbase = vb + vr * NTOK + vc;

    // prologue: load step-0 tiles into regs
    uint4 sKH = *(const uint4*)(Khi + kgbase);
    uint4 sKL = *(const uint4*)(Klo + kgbase);
    uint4 sVH = *(const uint4*)(Vhi + vgbase);
    uint4 sVL = *(const uint4*)(Vlo + vgbase);

    f32x4 o0 = {}, o1 = {};
    f32x4 lacc = {};
    float m_ = -1e30f;

    for (int step = 0; step < 64; ++step) {
        __syncthreads();                     // prev compute done: LDS overwritable
        *(uint4*)&KH[kr][kc] = sKH;          // implicit vmcnt wait (loads issued
        *(uint4*)&KL[kr][kc] = sKL;          //  one full step ago)
        *(uint4*)&VH[vr][vc] = sVH;
        *(uint4*)&VL[vr][vc] = sVL;
        __syncthreads();                     // tile visible

        // issue next-step loads now; land during this step's compute
        {
            const int nx = ((step + 1) & 63) * 64;   // wrap: reads valid, unused
            sKH = *(const uint4*)(Khi + kgbase + nx * HD);
            sKL = *(const uint4*)(Klo + kgbase + nx * HD);
            sVH = *(const uint4*)(Vhi + vgbase + nx);
            sVL = *(const uint4*)(Vlo + vgbase + nx);
        }

        // ---- K fragments from LDS ----
        bf16x8 kh[4], kl[4];
        #pragma unroll
        for (int t = 0; t < 4; ++t) {
            kh[t] = *(const bf16x8*)&KH[16 * t + lq][g * 8];
            kl[t] = *(const bf16x8*)&KL[16 * t + lq][g * 8];
        }

        // ---- QK^T (3-term split) ----
        f32x4 sc[4];
        #pragma unroll
        for (int t = 0; t < 4; ++t) {
            f32x4 cc = {0.f, 0.f, 0.f, 0.f};
            cc = __builtin_amdgcn_mfma_f32_16x16x32_bf16(kh[t], qh, cc, 0, 0, 0);
            cc = __builtin_amdgcn_mfma_f32_16x16x32_bf16(kh[t], ql, cc, 0, 0, 0);
            cc = __builtin_amdgcn_mfma_f32_16x16x32_bf16(kl[t], qh, cc, 0, 0, 0);
            sc[t] = cc;
        }

        // ---- online softmax ----
        float mx = fmaxf(
            fmaxf(fmaxf(fmaxf(sc[0][0], sc[0][1]), fmaxf(sc[0][2], sc[0][3])),
                  fmaxf(fmaxf(sc[1][0], sc[1][1]), fmaxf(sc[1][2], sc[1][3]))),
            fmaxf(fmaxf(fmaxf(sc[2][0], sc[2][1]), fmaxf(sc[2][2], sc[2][3])),
                  fmaxf(fmaxf(sc[3][0], sc[3][1]), fmaxf(sc[3][2], sc[3][3]))));
        mx = fmaxf(mx, __shfl_xor(mx, 16));
        mx = fmaxf(mx, __shfl_xor(mx, 32));
        mx = fmaxf(mx, m_);
        float rs = exp2_fast(m_ - mx);
        m_ = mx;
        lacc *= rs;
        o0 *= rs;
        o1 *= rs;

        unsigned ph[4][2];
        #pragma unroll
        for (int t = 0; t < 4; ++t) {
            float p0 = exp2_fast(sc[t][0] - mx);
            float p1 = exp2_fast(sc[t][1] - mx);
            float p2 = exp2_fast(sc[t][2] - mx);
            float p3 = exp2_fast(sc[t][3] - mx);
            lacc += (f32x4){p0, p1, p2, p3};
            ph[t][0] = cvt_pk_bf16(p0, p1);
            ph[t][1] = cvt_pk_bf16(p2, p3);
        }

        // ---- PV: redistribute P (C-frag -> B-frag), lazy V frags from LDS ----
        #pragma unroll
        for (int ks = 0; ks < 2; ++ks) {
            unsigned h00 = ph[2 * ks][0], h10 = ph[2 * ks + 1][0];
            unsigned h01 = ph[2 * ks][1], h11 = ph[2 * ks + 1][1];
            permlane_pv(h00, h10);
            permlane_pv(h01, h11);
            frag_u PH; PH.u = (u32x4){h00, h01, h10, h11};
            {
                bf16x8 vhf = *(const bf16x8*)&VH[lq][ks * 32 + g * 8];
                bf16x8 vlf = *(const bf16x8*)&VL[lq][ks * 32 + g * 8];
                o0 = __builtin_amdgcn_mfma_f32_16x16x32_bf16(vhf, PH.b, o0, 0, 0, 0);
                o0 = __builtin_amdgcn_mfma_f32_16x16x32_bf16(vlf, PH.b, o0, 0, 0, 0);
            }
            {
                bf16x8 vhf = *(const bf16x8*)&VH[16 + lq][ks * 32 + g * 8];
                bf16x8 vlf = *(const bf16x8*)&VL[16 + lq][ks * 32 + g * 8];
                o1 = __builtin_amdgcn_mfma_f32_16x16x32_bf16(vhf, PH.b, o1, 0, 0, 0);
                o1 = __builtin_amdgcn_mfma_f32_16x16x32_bf16(vlf, PH.b, o1, 0, 0, 0);
            }
        }
    }

    // ---- finalize: reduce l across g-groups, scale, store ----
    const int b_ = bh >> 3, h_ = bh & 7;
    float ls = (lacc[0] + lacc[1]) + (lacc[2] + lacc[3]);
    ls += __shfl_xor(ls, 16);
    ls += __shfl_xor(ls, 32);
    const float inv = 1.0f / ls;
    const int qg = q0 + lq;
    {
        float4 st;
        st.x = o0[0] * inv; st.y = o0[1] * inv;
        st.z = o0[2] * inv; st.w = o0[3] * inv;
        *(float4*)&AO[((size_t)b_ * NTOK + qg) * CDIM + h_ * 32 + g * 4] = st;
    }
    {
        float4 st;
        st.x = o1[0] * inv; st.y = o1[1] * inv;
        st.z = o1[2] * inv; st.w = o1[3] * inv;
        *(float4*)&AO[((size_t)b_ * NTOK + qg) * CDIM + h_ * 32 + 16 + g * 4] = st;
    }
}

// ---------------- Output projection GEMM (unchanged, working) ----------------
__global__ __launch_bounds__(256) void proj_gemm(
    const float* __restrict__ A, const float* __restrict__ W,
    const float* __restrict__ bias, float* __restrict__ out)
{
    __shared__ float As[BK][BM + 4];
    __shared__ float Bs[BK][BN + 4];

    const int tid = threadIdx.x;
    const int tx = tid & 15;
    const int ty = tid >> 4;
    const int row0 = blockIdx.x * BM;
    const int col0 = blockIdx.y * BN;

    float c[4][4] = {};

    for (int k0 = 0; k0 < CDIM; k0 += BK) {
        #pragma unroll
        for (int i = 0; i < 4; ++i) {
            int l = tid + i * 256;
            int r = l >> 4;
            int k4 = (l & 15) << 2;
            float4 v = *(const float4*)&A[(size_t)(row0 + r) * CDIM + k0 + k4];
            As[k4 + 0][r] = v.x; As[k4 + 1][r] = v.y;
            As[k4 + 2][r] = v.z; As[k4 + 3][r] = v.w;
        }
        #pragma unroll
        for (int i = 0; i < 4; ++i) {
            int l = tid + i * 256;
            int r = l >> 4;
            int c4 = (l & 15) << 2;
            *(float4*)&Bs[r][c4] = *(const float4*)&W[(size_t)(k0 + r) * CDIM + col0 + c4];
        }
        __syncthreads();

        #pragma unroll 16
        for (int kk = 0; kk < BK; ++kk) {
            float4 a = *(const float4*)&As[kk][ty << 2];
            float4 b = *(const float4*)&Bs[kk][tx << 2];
            float av[4] = {a.x, a.y, a.z, a.w};
            float bv[4] = {b.x, b.y, b.z, b.w};
            #pragma unroll
            for (int i = 0; i < 4; ++i)
                #pragma unroll
                for (int j = 0; j < 4; ++j)
                    c[i][j] = fmaf(av[i], bv[j], c[i][j]);
        }
        __syncthreads();
    }

    #pragma unroll
    for (int i = 0; i < 4; ++i) {
        int gr = row0 + (ty << 2) + i;
        #pragma unroll
        for (int j = 0; j < 4; ++j) {
            int gc = col0 + (tx << 2) + j;
            out[(size_t)gr * CDIM + gc] = c[i][j] + bias[gc];
        }
    }
}

extern "C" void kernel_launch(void* const* d_in, const int* in_sizes, int n_in,
                              void* d_out, int out_size, void* d_ws, size_t ws_size,
                              hipStream_t stream)
{
    const float* x      = (const float*)d_in[0];
    const float* w_qkv  = (const float*)d_in[1];
    const float* b_qkv  = (const float*)d_in[2];
    const float* w_proj = (const float*)d_in[3];
    const float* b_proj = (const float*)d_in[4];
    // d_in[5] rel_bias: per-head scalar over the full score matrix -> softmax no-op.

    float* out = (float*)d_out;

    // ws: Qhi|Qlo|Khi|Klo|Vhi|Vlo (4MB each, bf16) + AO (8MB f32) = 32MB
    const size_t NE = (size_t)BATCH * NH * NTOK * HD;   // 2,097,152
    char* p = (char*)d_ws;
    unsigned short* Qhi = (unsigned short*)p;  p += NE * 2;
    unsigned short* Qlo = (unsigned short*)p;  p += NE * 2;
    unsigned short* Khi = (unsigned short*)p;  p += NE * 2;
    unsigned short* Klo = (unsigned short*)p;  p += NE * 2;
    unsigned short* Vhi = (unsigned short*)p;  p += NE * 2;
    unsigned short* Vlo = (unsigned short*)p;  p += NE * 2;
    float* AO           = (float*)p;

    {
        dim3 grid(MROWS / BM, 768 / BN);   // 128 x 12
        qkv_gemm<<<grid, 256, 0, stream>>>(x, w_qkv, b_qkv, Qhi, Qlo, Khi, Klo, Vhi, Vlo);
    }
    {
        dim3 grid(1024);                   // 64 q-chunks x 16 bh (bh = bx & 15)
        attn_v6<<<grid, 256, 0, stream>>>(Qhi, Qlo, Khi, Klo, Vhi, Vlo, AO);
    }
    {
        dim3 grid(MROWS / BM, CDIM / BN);  // 128 x 4
        proj_gemm<<<grid, 256, 0, stream>>>(AO, w_proj, b_proj, out);
    }
}

// Round 8
// 210.716 us; speedup vs baseline: 1.7386x; 1.0019x over previous
//
#include <hip/hip_runtime.h>
#include <math.h>

#define BATCH 2
#define NTOK 4096        // H*W
#define CDIM 256
#define NH 8
#define HD 32
#define MROWS (BATCH * NTOK)   // 8192

typedef __attribute__((ext_vector_type(8))) short bf16x8;
typedef __attribute__((ext_vector_type(4))) float f32x4;
typedef __attribute__((ext_vector_type(4))) unsigned u32x4;

union frag_u { uint4 q; u32x4 u; bf16x8 b; };

__device__ __forceinline__ unsigned short f2bf(float f) {
    union { float f; unsigned u; } x; x.f = f;
    unsigned r = x.u + 0x7FFFu + ((x.u >> 16) & 1u);   // RNE
    return (unsigned short)(r >> 16);
}
__device__ __forceinline__ float bf2f(unsigned short h) {
    union { unsigned u; float f; } x; x.u = ((unsigned)h) << 16; return x.f;
}
__device__ __forceinline__ float exp2_fast(float x) {
    float r;
    asm("v_exp_f32 %0, %1\n\ts_nop 0" : "=v"(r) : "v"(x));   // proven r2-r5
    return r;
}
__device__ __forceinline__ unsigned cvt_pk_bf16(float a, float b) {
    unsigned r;   // lo16 = bf16(a), hi16 = bf16(b), RNE
    asm("v_cvt_pk_bf16_f32 %0, %1, %2" : "=v"(r) : "v"(a), "v"(b));
    return r;
}
// C-frag dword pair (tile 2ks, tile 2ks+1) -> B-frag dword pair (w0, w1); proven r3-r5
__device__ __forceinline__ void permlane_pv(unsigned &a, unsigned &b) {
    asm("s_nop 1\n\t"
        "v_permlane32_swap_b32 %0, %1\n\t"
        "s_nop 1\n\t"
        "v_permlane16_swap_b32 %0, %1" : "+v"(a), "+v"(b));
}

// ---------------- QKV projection GEMM (unchanged, working) ----------------
#define BM 64
#define BN 64
#define BK 64

__global__ __launch_bounds__(256) void qkv_gemm(
    const float* __restrict__ X, const float* __restrict__ W,
    const float* __restrict__ bias,
    unsigned short* __restrict__ Qhi, unsigned short* __restrict__ Qlo,
    unsigned short* __restrict__ Khi, unsigned short* __restrict__ Klo,
    unsigned short* __restrict__ Vhi, unsigned short* __restrict__ Vlo)
{
    __shared__ float As[BK][BM + 4];
    __shared__ float Bs[BK][BN + 4];

    const int tid = threadIdx.x;
    const int tx = tid & 15;
    const int ty = tid >> 4;
    const int row0 = blockIdx.x * BM;
    const int col0 = blockIdx.y * BN;

    float c[4][4] = {};

    for (int k0 = 0; k0 < CDIM; k0 += BK) {
        #pragma unroll
        for (int i = 0; i < 4; ++i) {
            int l = tid + i * 256;
            int r = l >> 4;
            int k4 = (l & 15) << 2;
            float4 v = *(const float4*)&X[(size_t)(row0 + r) * CDIM + k0 + k4];
            As[k4 + 0][r] = v.x; As[k4 + 1][r] = v.y;
            As[k4 + 2][r] = v.z; As[k4 + 3][r] = v.w;
        }
        #pragma unroll
        for (int i = 0; i < 4; ++i) {
            int l = tid + i * 256;
            int r = l >> 4;
            int c4 = (l & 15) << 2;
            *(float4*)&Bs[r][c4] = *(const float4*)&W[(size_t)(k0 + r) * 768 + col0 + c4];
        }
        __syncthreads();

        #pragma unroll 16
        for (int kk = 0; kk < BK; ++kk) {
            float4 a = *(const float4*)&As[kk][ty << 2];
            float4 b = *(const float4*)&Bs[kk][tx << 2];
            float av[4] = {a.x, a.y, a.z, a.w};
            float bv[4] = {b.x, b.y, b.z, b.w};
            #pragma unroll
            for (int i = 0; i < 4; ++i)
                #pragma unroll
                for (int j = 0; j < 4; ++j)
                    c[i][j] = fmaf(av[i], bv[j], c[i][j]);
        }
        __syncthreads();
    }

    const int s = col0 >> 8;            // 0=Q 1=K 2=V
    const int b_ = row0 >> 12;
    const int n0 = (row0 & (NTOK - 1)) + (ty << 2);
    const int gc0 = col0 + (tx << 2);
    const int h  = (gc0 >> 5) & 7;
    const int e0 = gc0 & 31;
    const int bh = b_ * NH + h;
    // scale/sqrt(hd) * log2(e): QK^T lands directly in log2 domain
    const float QSC = (float)(1.4426950408889634 / 5.656854249492381);

    if (s == 0) {
        #pragma unroll
        for (int i = 0; i < 4; ++i) {
            unsigned short hh[4], ll[4];
            #pragma unroll
            for (int j = 0; j < 4; ++j) {
                float v = (c[i][j] + bias[gc0 + j]) * QSC;
                hh[j] = f2bf(v);
                ll[j] = f2bf(v - bf2f(hh[j]));
            }
            size_t idx = ((size_t)bh * NTOK + n0 + i) * HD + e0;
            uint2 hw; hw.x = hh[0] | ((unsigned)hh[1] << 16); hw.y = hh[2] | ((unsigned)hh[3] << 16);
            uint2 lw; lw.x = ll[0] | ((unsigned)ll[1] << 16); lw.y = ll[2] | ((unsigned)ll[3] << 16);
            *(uint2*)&Qhi[idx] = hw;
            *(uint2*)&Qlo[idx] = lw;
        }
    } else if (s == 1) {
        #pragma unroll
        for (int i = 0; i < 4; ++i) {
            unsigned short hh[4], ll[4];
            #pragma unroll
            for (int j = 0; j < 4; ++j) {
                float v = c[i][j] + bias[gc0 + j];
                hh[j] = f2bf(v);
                ll[j] = f2bf(v - bf2f(hh[j]));
            }
            size_t idx = ((size_t)bh * NTOK + n0 + i) * HD + e0;
            uint2 hw; hw.x = hh[0] | ((unsigned)hh[1] << 16); hw.y = hh[2] | ((unsigned)hh[3] << 16);
            uint2 lw; lw.x = ll[0] | ((unsigned)ll[1] << 16); lw.y = ll[2] | ((unsigned)ll[3] << 16);
            *(uint2*)&Khi[idx] = hw;
            *(uint2*)&Klo[idx] = lw;
        }
    } else {
        // V transposed: [bh][e][n]
        #pragma unroll
        for (int j = 0; j < 4; ++j) {
            unsigned short hh[4], ll[4];
            #pragma unroll
            for (int i = 0; i < 4; ++i) {
                float v = c[i][j] + bias[gc0 + j];
                hh[i] = f2bf(v);
                ll[i] = f2bf(v - bf2f(hh[i]));
            }
            size_t idx = ((size_t)bh * HD + e0 + j) * NTOK + n0;
            uint2 hw; hw.x = hh[0] | ((unsigned)hh[1] << 16); hw.y = hh[2] | ((unsigned)hh[3] << 16);
            uint2 lw; lw.x = ll[0] | ((unsigned)ll[1] << 16); lw.y = ll[2] | ((unsigned)ll[3] << 16);
            *(uint2*)&Vhi[idx] = hw;
            *(uint2*)&Vlo[idx] = lw;
        }
    }
}

// ---------------- MFMA flash attention v6: 16 q-rows/wave, K+V in LDS ----------------
// Block = 4 waves x 16 q-rows = 64 q-rows; grid = 64 q-chunks x 16 bh = 1024
// blocks -> 4 blocks/CU, target 16 waves/CU (50% occ) at VGPR<=128.
// K+V single-buffered in LDS; step s+1 prefetched into regs right after the
// visibility barrier (full compute phase covers L2 latency; pre-write vmcnt
// waits on loads issued one whole step earlier). Two barriers per step.
// All global offsets 32-bit. Math identical to r5 (3-term QK, single-bf16 P
// via cvt_pk+permlane, 2-term PV, exp2 domain).
__global__ __launch_bounds__(256, 3) void attn_v6(
    const unsigned short* __restrict__ Qhi, const unsigned short* __restrict__ Qlo,
    const unsigned short* __restrict__ Khi, const unsigned short* __restrict__ Klo,
    const unsigned short* __restrict__ Vhi, const unsigned short* __restrict__ Vlo,
    float* __restrict__ AO)
{
    __shared__ __align__(16) unsigned short KH[64][44], KL[64][44];   // pitch 88B
    __shared__ __align__(16) unsigned short VH[32][72], VL[32][72];   // pitch 144B

    const int tid = threadIdx.x;
    const int w = tid >> 6, lane = tid & 63, lq = lane & 15, g = lane >> 4;
    const int bx = blockIdx.x;
    const int bh = bx & 15, qc = bx >> 4;     // same-head blocks share XCD L2
    const int q0 = qc * 64 + w * 16;
    const int kb = bh * (NTOK * HD);          // fits 32-bit (max 2M)
    const int vb = bh * (HD * NTOK);

    // ---- Q fragment (pre-scaled by scale*log2e) ----
    bf16x8 qh, ql;
    {
        const int qi = kb + (q0 + lq) * HD + g * 8;
        qh = *(const bf16x8*)(Qhi + qi);
        ql = *(const bf16x8*)(Qlo + qi);
    }

    // ---- staging slots: K row 0..63 / 16B chunk; V row 0..31 / 16B chunk ----
    const int kr = tid >> 2, kc = (tid & 3) << 3;
    const int vr = tid >> 3, vc = (tid & 7) << 3;
    const int kgbase = kb + kr * HD + kc;
    const int vgbase = vb + vr * NTOK + vc;

    // prologue: load step-0 tiles into regs
    uint4 sKH = *(const uint4*)(Khi + kgbase);
    uint4 sKL = *(const uint4*)(Klo + kgbase);
    uint4 sVH = *(const uint4*)(Vhi + vgbase);
    uint4 sVL = *(const uint4*)(Vlo + vgbase);

    f32x4 o0 = {}, o1 = {};
    f32x4 lacc = {};
    float m_ = -1e30f;

    for (int step = 0; step < 64; ++step) {
        __syncthreads();                     // prev compute done: LDS overwritable
        *(uint4*)&KH[kr][kc] = sKH;          // implicit vmcnt wait (loads issued
        *(uint4*)&KL[kr][kc] = sKL;          //  one full step ago)
        *(uint4*)&VH[vr][vc] = sVH;
        *(uint4*)&VL[vr][vc] = sVL;
        __syncthreads();                     // tile visible

        // issue next-step loads now; land during this step's compute
        {
            const int nx = ((step + 1) & 63) * 64;   // wrap: reads valid, unused
            sKH = *(const uint4*)(Khi + kgbase + nx * HD);
            sKL = *(const uint4*)(Klo + kgbase + nx * HD);
            sVH = *(const uint4*)(Vhi + vgbase + nx);
            sVL = *(const uint4*)(Vlo + vgbase + nx);
        }

        // ---- K fragments from LDS ----
        bf16x8 kh[4], kl[4];
        #pragma unroll
        for (int t = 0; t < 4; ++t) {
            kh[t] = *(const bf16x8*)&KH[16 * t + lq][g * 8];
            kl[t] = *(const bf16x8*)&KL[16 * t + lq][g * 8];
        }

        // ---- QK^T (3-term split) ----
        f32x4 sc[4];
        #pragma unroll
        for (int t = 0; t < 4; ++t) {
            f32x4 cc = {0.f, 0.f, 0.f, 0.f};
            cc = __builtin_amdgcn_mfma_f32_16x16x32_bf16(kh[t], qh, cc, 0, 0, 0);
            cc = __builtin_amdgcn_mfma_f32_16x16x32_bf16(kh[t], ql, cc, 0, 0, 0);
            cc = __builtin_amdgcn_mfma_f32_16x16x32_bf16(kl[t], qh, cc, 0, 0, 0);
            sc[t] = cc;
        }

        // ---- online softmax ----
        float mx = fmaxf(
            fmaxf(fmaxf(fmaxf(sc[0][0], sc[0][1]), fmaxf(sc[0][2], sc[0][3])),
                  fmaxf(fmaxf(sc[1][0], sc[1][1]), fmaxf(sc[1][2], sc[1][3]))),
            fmaxf(fmaxf(fmaxf(sc[2][0], sc[2][1]), fmaxf(sc[2][2], sc[2][3])),
                  fmaxf(fmaxf(sc[3][0], sc[3][1]), fmaxf(sc[3][2], sc[3][3]))));
        mx = fmaxf(mx, __shfl_xor(mx, 16));
        mx = fmaxf(mx, __shfl_xor(mx, 32));
        mx = fmaxf(mx, m_);
        float rs = exp2_fast(m_ - mx);
        m_ = mx;
        lacc *= rs;
        o0 *= rs;
        o1 *= rs;

        unsigned ph[4][2];
        #pragma unroll
        for (int t = 0; t < 4; ++t) {
            float p0 = exp2_fast(sc[t][0] - mx);
            float p1 = exp2_fast(sc[t][1] - mx);
            float p2 = exp2_fast(sc[t][2] - mx);
            float p3 = exp2_fast(sc[t][3] - mx);
            lacc += (f32x4){p0, p1, p2, p3};
            ph[t][0] = cvt_pk_bf16(p0, p1);
            ph[t][1] = cvt_pk_bf16(p2, p3);
        }

        // ---- PV: redistribute P (C-frag -> B-frag), lazy V frags from LDS ----
        #pragma unroll
        for (int ks = 0; ks < 2; ++ks) {
            unsigned h00 = ph[2 * ks][0], h10 = ph[2 * ks + 1][0];
            unsigned h01 = ph[2 * ks][1], h11 = ph[2 * ks + 1][1];
            permlane_pv(h00, h10);
            permlane_pv(h01, h11);
            frag_u PH; PH.u = (u32x4){h00, h01, h10, h11};
            {
                bf16x8 vhf = *(const bf16x8*)&VH[lq][ks * 32 + g * 8];
                bf16x8 vlf = *(const bf16x8*)&VL[lq][ks * 32 + g * 8];
                o0 = __builtin_amdgcn_mfma_f32_16x16x32_bf16(vhf, PH.b, o0, 0, 0, 0);
                o0 = __builtin_amdgcn_mfma_f32_16x16x32_bf16(vlf, PH.b, o0, 0, 0, 0);
            }
            {
                bf16x8 vhf = *(const bf16x8*)&VH[16 + lq][ks * 32 + g * 8];
                bf16x8 vlf = *(const bf16x8*)&VL[16 + lq][ks * 32 + g * 8];
                o1 = __builtin_amdgcn_mfma_f32_16x16x32_bf16(vhf, PH.b, o1, 0, 0, 0);
                o1 = __builtin_amdgcn_mfma_f32_16x16x32_bf16(vlf, PH.b, o1, 0, 0, 0);
            }
        }
    }

    // ---- finalize: reduce l across g-groups, scale, store ----
    const int b_ = bh >> 3, h_ = bh & 7;
    float ls = (lacc[0] + lacc[1]) + (lacc[2] + lacc[3]);
    ls += __shfl_xor(ls, 16);
    ls += __shfl_xor(ls, 32);
    const float inv = 1.0f / ls;
    const int qg = q0 + lq;
    {
        float4 st;
        st.x = o0[0] * inv; st.y = o0[1] * inv;
        st.z = o0[2] * inv; st.w = o0[3] * inv;
        *(float4*)&AO[((size_t)b_ * NTOK + qg) * CDIM + h_ * 32 + g * 4] = st;
    }
    {
        float4 st;
        st.x = o1[0] * inv; st.y = o1[1] * inv;
        st.z = o1[2] * inv; st.w = o1[3] * inv;
        *(float4*)&AO[((size_t)b_ * NTOK + qg) * CDIM + h_ * 32 + 16 + g * 4] = st;
    }
}

// ---------------- Output projection GEMM (unchanged, working) ----------------
__global__ __launch_bounds__(256) void proj_gemm(
    const float* __restrict__ A, const float* __restrict__ W,
    const float* __restrict__ bias, float* __restrict__ out)
{
    __shared__ float As[BK][BM + 4];
    __shared__ float Bs[BK][BN + 4];

    const int tid = threadIdx.x;
    const int tx = tid & 15;
    const int ty = tid >> 4;
    const int row0 = blockIdx.x * BM;
    const int col0 = blockIdx.y * BN;

    float c[4][4] = {};

    for (int k0 = 0; k0 < CDIM; k0 += BK) {
        #pragma unroll
        for (int i = 0; i < 4; ++i) {
            int l = tid + i * 256;
            int r = l >> 4;
            int k4 = (l & 15) << 2;
            float4 v = *(const float4*)&A[(size_t)(row0 + r) * CDIM + k0 + k4];
            As[k4 + 0][r] = v.x; As[k4 + 1][r] = v.y;
            As[k4 + 2][r] = v.z; As[k4 + 3][r] = v.w;
        }
        #pragma unroll
        for (int i = 0; i < 4; ++i) {
            int l = tid + i * 256;
            int r = l >> 4;
            int c4 = (l & 15) << 2;
            *(float4*)&Bs[r][c4] = *(const float4*)&W[(size_t)(k0 + r) * CDIM + col0 + c4];
        }
        __syncthreads();

        #pragma unroll 16
        for (int kk = 0; kk < BK; ++kk) {
            float4 a = *(const float4*)&As[kk][ty << 2];
            float4 b = *(const float4*)&Bs[kk][tx << 2];
            float av[4] = {a.x, a.y, a.z, a.w};
            float bv[4] = {b.x, b.y, b.z, b.w};
            #pragma unroll
            for (int i = 0; i < 4; ++i)
                #pragma unroll
                for (int j = 0; j < 4; ++j)
                    c[i][j] = fmaf(av[i], bv[j], c[i][j]);
        }
        __syncthreads();
    }

    #pragma unroll
    for (int i = 0; i < 4; ++i) {
        int gr = row0 + (ty << 2) + i;
        #pragma unroll
        for (int j = 0; j < 4; ++j) {
            int gc = col0 + (tx << 2) + j;
            out[(size_t)gr * CDIM + gc] = c[i][j] + bias[gc];
        }
    }
}

extern "C" void kernel_launch(void* const* d_in, const int* in_sizes, int n_in,
                              void* d_out, int out_size, void* d_ws, size_t ws_size,
                              hipStream_t stream)
{
    const float* x      = (const float*)d_in[0];
    const float* w_qkv  = (const float*)d_in[1];
    const float* b_qkv  = (const float*)d_in[2];
    const float* w_proj = (const float*)d_in[3];
    const float* b_proj = (const float*)d_in[4];
    // d_in[5] rel_bias: per-head scalar over the full score matrix -> softmax no-op.

    float* out = (float*)d_out;

    // ws: Qhi|Qlo|Khi|Klo|Vhi|Vlo (4MB each, bf16) + AO (8MB f32) = 32MB
    const size_t NE = (size_t)BATCH * NH * NTOK * HD;   // 2,097,152
    char* p = (char*)d_ws;
    unsigned short* Qhi = (unsigned short*)p;  p += NE * 2;
    unsigned short* Qlo = (unsigned short*)p;  p += NE * 2;
    unsigned short* Khi = (unsigned short*)p;  p += NE * 2;
    unsigned short* Klo = (unsigned short*)p;  p += NE * 2;
    unsigned short* Vhi = (unsigned short*)p;  p += NE * 2;
    unsigned short* Vlo = (unsigned short*)p;  p += NE * 2;
    float* AO           = (float*)p;

    {
        dim3 grid(MROWS / BM, 768 / BN);   // 128 x 12
        qkv_gemm<<<grid, 256, 0, stream>>>(x, w_qkv, b_qkv, Qhi, Qlo, Khi, Klo, Vhi, Vlo);
    }
    {
        dim3 grid(1024);                   // 64 q-chunks x 16 bh (bh = bx & 15)
        attn_v6<<<grid, 256, 0, stream>>>(Qhi, Qlo, Khi, Klo, Vhi, Vlo, AO);
    }
    {
        dim3 grid(MROWS / BM, CDIM / BN);  // 128 x 4
        proj_gemm<<<grid, 256, 0, stream>>>(AO, w_proj, b_proj, out);
    }
}